// Round 12
// baseline (346.815 us; speedup 1.0000x reference)
//
#include <hip/hip_runtime.h>

// R12: R11 (32x32 MFMA, 2-wave/64-row items, persistent queue) with SINGLE
// LDS buffer (16.5 KB/block -> 8 blocks/CU, 4 waves/SIMD, grid 2048).
// Reg-staging keeps the 1-tile prefetch: regs hold tile t+1 while LDS holds
// tile t; ds_write moved into the inter-barrier serial section (hidden by
// doubled TLP per m114 cross-block overlap). Math/prep/queue identical.

#define BB 4
#define QQ 1024
#define SS 2048
#define HH 32
#define DD 128
#define QT 64
#define KT 32
#define NTILES 64
#define TILE_ELEMS 4096
#define NITEMS 2048

typedef __attribute__((ext_vector_type(8))) short short8;
typedef __attribute__((ext_vector_type(4))) float f32x4;
typedef __attribute__((ext_vector_type(16))) float f32x16;
typedef __attribute__((ext_vector_type(4))) unsigned int u32x4;
typedef __attribute__((ext_vector_type(8))) unsigned short u16x8;

__device__ __forceinline__ unsigned short f2bf(float f) {
    unsigned int u = __builtin_bit_cast(unsigned int, f);
    u += 0x7FFFu + ((u >> 16) & 1u);
    return (unsigned short)(u >> 16);
}
__device__ __forceinline__ unsigned int cvtpk(float lo, float hi) {
    unsigned int r;
    asm("v_cvt_pk_bf16_f32 %0, %1, %2" : "=v"(r) : "v"(lo), "v"(hi));
    return r;
}

// ---------------- prep: f32 cache/new -> bf16 32x32-fragment-ordered ws -------
// K tile (4096 hw): idx = c*512 + l*8 + e  ->  K[key=(l&31)][d = c*16 + (l>>5)*8 + e]
// V tile (4096 hw): idx = a*512 + l*8 + e, a=dchunk*2+kc
//                   ->  V[key = kc*16 + (l>>5)*8 + e][d = dchunk*32 + (l&31)]
__global__ __launch_bounds__(256)
void prep(const float* __restrict__ ks, const float* __restrict__ vs,
          const float* __restrict__ kc_, const float* __restrict__ vc,
          const int* __restrict__ qlens, const int* __restrict__ clens,
          unsigned short* __restrict__ Kws, unsigned short* __restrict__ Vws)
{
    const int tile = blockIdx.x, h = blockIdx.y, b = blockIdx.z;
    const int qlen = qlens[b], clen = clens[b];
    if (tile * KT >= clen + qlen) return;
    const int tid = threadIdx.x;
    unsigned short* kout = Kws + (((size_t)b * HH + h) * NTILES + tile) * TILE_ELEMS;
    unsigned short* vout = Vws + (((size_t)b * HH + h) * NTILES + tile) * TILE_ELEMS;

    #pragma unroll
    for (int h2 = 0; h2 < 2; ++h2) {
        const int idx8 = h2 * 2048 + tid * 8;
        const int c = idx8 >> 9, l = (idx8 >> 3) & 63;
        int key = tile * KT + (l & 31);
        const float* src;
        if (key < clen) {
            src = kc_ + (((size_t)b * SS + key) * HH + h) * DD;
        } else {
            int i2 = key - clen; if (i2 > QQ - 1) i2 = QQ - 1;
            src = ks + (((size_t)b * QQ + i2) * HH + h) * DD;
        }
        const int d0 = c * 16 + ((l >> 5) << 3);
        f32x4 a0 = *(const f32x4*)&src[d0];
        f32x4 a1 = *(const f32x4*)&src[d0 + 4];
        u16x8 w;
        w[0] = f2bf(a0[0]); w[1] = f2bf(a0[1]); w[2] = f2bf(a0[2]); w[3] = f2bf(a0[3]);
        w[4] = f2bf(a1[0]); w[5] = f2bf(a1[1]); w[6] = f2bf(a1[2]); w[7] = f2bf(a1[3]);
        *(u16x8*)&kout[idx8] = w;
    }
    #pragma unroll
    for (int h2 = 0; h2 < 2; ++h2) {
        const int idx8 = h2 * 2048 + tid * 8;
        const int a = idx8 >> 9, l = (idx8 >> 3) & 63;
        const int dchunk = a >> 1, kcc = a & 1;
        const int d = dchunk * 32 + (l & 31);
        const int kb = tile * KT + kcc * 16 + ((l >> 5) << 3);
        u16x8 w;
        #pragma unroll
        for (int e = 0; e < 8; ++e) {
            int key = kb + e;
            const float* src;
            if (key < clen) {
                src = vc + (((size_t)b * SS + key) * HH + h) * DD;
            } else {
                int i2 = key - clen; if (i2 > QQ - 1) i2 = QQ - 1;
                src = vs + (((size_t)b * QQ + i2) * HH + h) * DD;
            }
            w[e] = f2bf(src[d]);
        }
        *(u16x8*)&vout[idx8] = w;
    }
}

// ---------------- hot: 128-thr blocks, single LDS buf, 8 blocks/CU ----------
__global__ __launch_bounds__(128, 4)
void segattn_persist(const float* __restrict__ qs, const int* __restrict__ qlens,
                     const int* __restrict__ clens,
                     const unsigned short* __restrict__ Kws,
                     const unsigned short* __restrict__ Vws,
                     float* __restrict__ out, int* __restrict__ counter)
{
    __shared__ int s_item;
    alignas(16) __shared__ unsigned short KVl[8192];  // K [0,4096) V [4096,8192)

    const int tid = threadIdx.x, w = tid >> 6, lane = tid & 63;
    const int q31 = lane & 31, hi = lane >> 5;
    const bool hiL = (hi != 0);
    const float psc = 0.08838834764831845f * 1.4426950408889634f;
    const int sbase = w * 2048 + lane * 8;   // this wave's staging slice base (hw)

    for (;;) {
        if (tid == 0) s_item = atomicAdd(counter, 1);
        __syncthreads();
        const int idx = s_item;
        __syncthreads();
        if (idx >= NITEMS) break;

        const int qt = 15 - (idx >> 7);      // heavy-first pop order (LPT)
        const int b = idx & 3, h = (idx >> 2) & 31;
        const int qlen = qlens[b], clen = clens[b];
        const int q0 = qt * QT;

        if (q0 >= qlen) {                    // fully padded tile -> zeros
            f32x4 z = {0.f, 0.f, 0.f, 0.f};
            #pragma unroll
            for (int i2 = 0; i2 < 16; ++i2) {
                int f = tid + i2 * 128;
                int r = f >> 5, d4 = f & 31;
                *(f32x4*)&out[(((size_t)b * QQ + q0 + r) * HH + h) * DD + d4 * 4] = z;
            }
            continue;
        }

        const int q = q0 + w * 32 + q31;
        const float* qp = qs + (((size_t)b * QQ + q) * HH + h) * DD;
        short8 qf[8];
        #pragma unroll
        for (int c = 0; c < 8; ++c) {
            const int d0 = c * 16 + hi * 8;
            f32x4 a0 = *(const f32x4*)&qp[d0];
            f32x4 a1 = *(const f32x4*)&qp[d0 + 4];
            short8 t;
            t[0] = (short)f2bf(a0[0] * psc); t[1] = (short)f2bf(a0[1] * psc);
            t[2] = (short)f2bf(a0[2] * psc); t[3] = (short)f2bf(a0[3] * psc);
            t[4] = (short)f2bf(a1[0] * psc); t[5] = (short)f2bf(a1[1] * psc);
            t[6] = (short)f2bf(a1[2] * psc); t[7] = (short)f2bf(a1[3] * psc);
            qf[c] = t;
        }

        const int lim_l = (q < qlen) ? (clen + q + 1) : 0;
        const int wq0 = q0 + w * 32;
        const int lim_min = (wq0 + 31 < qlen) ? (clen + wq0 + 1) : 0;

        float m_ = -3e38f, l_ = 0.f;         // lane-partial (pair-reduced at end)
        f32x16 o0 = {0}, o1 = {0}, o2 = {0}, o3 = {0};

        const int kmax = clen + min(q0 + QT, qlen);
        const int nt = (kmax + KT - 1) / KT;
        const unsigned short* Kb = Kws + ((size_t)(b * HH + h)) * NTILES * TILE_ELEMS;
        const unsigned short* Vb = Vws + ((size_t)(b * HH + h)) * NTILES * TILE_ELEMS;

        // ---- prologue: reg-stage tile 0
        u32x4 sk0 = *(const u32x4*)&Kb[sbase];
        u32x4 sk1 = *(const u32x4*)&Kb[sbase + 512];
        u32x4 sk2 = *(const u32x4*)&Kb[sbase + 1024];
        u32x4 sk3 = *(const u32x4*)&Kb[sbase + 1536];
        u32x4 sv0 = *(const u32x4*)&Vb[sbase];
        u32x4 sv1 = *(const u32x4*)&Vb[sbase + 512];
        u32x4 sv2 = *(const u32x4*)&Vb[sbase + 1024];
        u32x4 sv3 = *(const u32x4*)&Vb[sbase + 1536];

        for (int t = 0; t < nt; ++t) {
            // publish tile t (in regs) into the single buffer
            *(u32x4*)&KVl[sbase]               = sk0;
            *(u32x4*)&KVl[sbase + 512]         = sk1;
            *(u32x4*)&KVl[sbase + 1024]        = sk2;
            *(u32x4*)&KVl[sbase + 1536]        = sk3;
            *(u32x4*)&KVl[4096 + sbase]        = sv0;
            *(u32x4*)&KVl[4096 + sbase + 512]  = sv1;
            *(u32x4*)&KVl[4096 + sbase + 1024] = sv2;
            *(u32x4*)&KVl[4096 + sbase + 1536] = sv3;
            // issue loads for tile t+1 (land during compute below)
            const int tnx = (t + 1 < nt) ? t + 1 : (nt - 1);
            const unsigned short* ktn = Kb + (size_t)tnx * TILE_ELEMS;
            const unsigned short* vtn = Vb + (size_t)tnx * TILE_ELEMS;
            sk0 = *(const u32x4*)&ktn[sbase];
            sk1 = *(const u32x4*)&ktn[sbase + 512];
            sk2 = *(const u32x4*)&ktn[sbase + 1024];
            sk3 = *(const u32x4*)&ktn[sbase + 1536];
            sv0 = *(const u32x4*)&vtn[sbase];
            sv1 = *(const u32x4*)&vtn[sbase + 512];
            sv2 = *(const u32x4*)&vtn[sbase + 1024];
            sv3 = *(const u32x4*)&vtn[sbase + 1536];
            asm volatile("s_waitcnt lgkmcnt(0)" ::: "memory");
            __builtin_amdgcn_s_barrier();          // buffer published
            __builtin_amdgcn_sched_barrier(0);

            // ---- compute tile t
            const int pbase = t * KT;
            f32x16 s = {0};
            #pragma unroll
            for (int c = 0; c < 8; ++c) {
                short8 kf = *(const short8*)&KVl[c * 512 + lane * 8];
                s = __builtin_amdgcn_mfma_f32_32x32x16_bf16(kf, qf[c], s, 0, 0, 0);
            }
            if (pbase + KT > lim_min) {
                #pragma unroll
                for (int r = 0; r < 16; ++r) {
                    const int kk = pbase + (r & 3) + ((r >> 2) << 3) + hi * 4;
                    if (kk >= lim_l) s[r] = -3e38f;
                }
            }
            float pm = fmaxf(fmaxf(fmaxf(fmaxf(s[0], s[1]), fmaxf(s[2], s[3])),
                                   fmaxf(fmaxf(s[4], s[5]), fmaxf(s[6], s[7]))),
                             fmaxf(fmaxf(fmaxf(s[8], s[9]), fmaxf(s[10], s[11])),
                                   fmaxf(fmaxf(s[12], s[13]), fmaxf(s[14], s[15]))));
            if (__any(pm > m_ + 8.0f)) {
                pm = fmaxf(pm, __shfl_xor(pm, 32));
                const float mn = fmaxf(m_, pm);
                const float alpha = __builtin_amdgcn_exp2f(m_ - mn);
                m_ = mn;
                l_ *= alpha;
                #pragma unroll
                for (int r = 0; r < 16; ++r) {
                    o0[r] *= alpha; o1[r] *= alpha; o2[r] *= alpha; o3[r] *= alpha;
                }
            }
            float p[16];
            #pragma unroll
            for (int r = 0; r < 16; ++r) p[r] = __builtin_amdgcn_exp2f(s[r] - m_);
            l_ += (((p[0]+p[1])+(p[2]+p[3])) + ((p[4]+p[5])+(p[6]+p[7])))
                + (((p[8]+p[9])+(p[10]+p[11])) + ((p[12]+p[13])+(p[14]+p[15])));

            const unsigned int w0 = cvtpk(p[0],  p[1]);
            const unsigned int w1 = cvtpk(p[2],  p[3]);
            const unsigned int w2 = cvtpk(p[4],  p[5]);
            const unsigned int w3 = cvtpk(p[6],  p[7]);
            const unsigned int w4 = cvtpk(p[8],  p[9]);
            const unsigned int w5 = cvtpk(p[10], p[11]);
            const unsigned int w6 = cvtpk(p[12], p[13]);
            const unsigned int w7 = cvtpk(p[14], p[15]);
            const unsigned int x0 = (unsigned int)__shfl_xor((int)w0, 32);
            const unsigned int x1 = (unsigned int)__shfl_xor((int)w1, 32);
            const unsigned int x2 = (unsigned int)__shfl_xor((int)w2, 32);
            const unsigned int x3 = (unsigned int)__shfl_xor((int)w3, 32);
            const unsigned int x4 = (unsigned int)__shfl_xor((int)w4, 32);
            const unsigned int x5 = (unsigned int)__shfl_xor((int)w5, 32);
            const unsigned int x6 = (unsigned int)__shfl_xor((int)w6, 32);
            const unsigned int x7 = (unsigned int)__shfl_xor((int)w7, 32);
            u32x4 pb0w, pb1w;
            pb0w[0] = hiL ? x2 : w0;  pb0w[1] = hiL ? x3 : w1;
            pb0w[2] = hiL ? w2 : x0;  pb0w[3] = hiL ? w3 : x1;
            pb1w[0] = hiL ? x6 : w4;  pb1w[1] = hiL ? x7 : w5;
            pb1w[2] = hiL ? w6 : x4;  pb1w[3] = hiL ? w7 : x5;
            const short8 pb0 = __builtin_bit_cast(short8, pb0w);
            const short8 pb1 = __builtin_bit_cast(short8, pb1w);

            {
                short8 va = *(const short8*)&KVl[4096 + 0 * 512 + lane * 8];
                short8 vb = *(const short8*)&KVl[4096 + 1 * 512 + lane * 8];
                o0 = __builtin_amdgcn_mfma_f32_32x32x16_bf16(va, pb0, o0, 0, 0, 0);
                o0 = __builtin_amdgcn_mfma_f32_32x32x16_bf16(vb, pb1, o0, 0, 0, 0);
            }
            {
                short8 va = *(const short8*)&KVl[4096 + 2 * 512 + lane * 8];
                short8 vb = *(const short8*)&KVl[4096 + 3 * 512 + lane * 8];
                o1 = __builtin_amdgcn_mfma_f32_32x32x16_bf16(va, pb0, o1, 0, 0, 0);
                o1 = __builtin_amdgcn_mfma_f32_32x32x16_bf16(vb, pb1, o1, 0, 0, 0);
            }
            {
                short8 va = *(const short8*)&KVl[4096 + 4 * 512 + lane * 8];
                short8 vb = *(const short8*)&KVl[4096 + 5 * 512 + lane * 8];
                o2 = __builtin_amdgcn_mfma_f32_32x32x16_bf16(va, pb0, o2, 0, 0, 0);
                o2 = __builtin_amdgcn_mfma_f32_32x32x16_bf16(vb, pb1, o2, 0, 0, 0);
            }
            {
                short8 va = *(const short8*)&KVl[4096 + 6 * 512 + lane * 8];
                short8 vb = *(const short8*)&KVl[4096 + 7 * 512 + lane * 8];
                o3 = __builtin_amdgcn_mfma_f32_32x32x16_bf16(va, pb0, o3, 0, 0, 0);
                o3 = __builtin_amdgcn_mfma_f32_32x32x16_bf16(vb, pb1, o3, 0, 0, 0);
            }

            asm volatile("s_waitcnt lgkmcnt(0)" ::: "memory");
            __builtin_amdgcn_s_barrier();          // all waves done reading buf
            __builtin_amdgcn_sched_barrier(0);
        }

        // ---- epilogue: pair-reduce l, store O
        float lt = l_ + __shfl_xor(l_, 32);
        const bool val = (q < qlen);
        const float inv = val ? (1.0f / lt) : 0.f;
        float* op = out + (((size_t)b * QQ + q) * HH + h) * DD;
        #pragma unroll
        for (int rr = 0; rr < 4; ++rr) {
            f32x4 wv;
            const int d0 = rr * 8 + hi * 4;
            wv[0] = o0[rr*4+0]*inv; wv[1] = o0[rr*4+1]*inv;
            wv[2] = o0[rr*4+2]*inv; wv[3] = o0[rr*4+3]*inv;
            *(f32x4*)&op[d0] = wv;
            wv[0] = o1[rr*4+0]*inv; wv[1] = o1[rr*4+1]*inv;
            wv[2] = o1[rr*4+2]*inv; wv[3] = o1[rr*4+3]*inv;
            *(f32x4*)&op[32 + d0] = wv;
            wv[0] = o2[rr*4+0]*inv; wv[1] = o2[rr*4+1]*inv;
            wv[2] = o2[rr*4+2]*inv; wv[3] = o2[rr*4+3]*inv;
            *(f32x4*)&op[64 + d0] = wv;
            wv[0] = o3[rr*4+0]*inv; wv[1] = o3[rr*4+1]*inv;
            wv[2] = o3[rr*4+2]*inv; wv[3] = o3[rr*4+3]*inv;
            *(f32x4*)&op[96 + d0] = wv;
        }
    }
}

// ---------------- R1 fallback (proven) if ws too small ----------------
__global__ __launch_bounds__(256)
void segattn(const float* __restrict__ qs, const float* __restrict__ ks,
             const float* __restrict__ vs, const float* __restrict__ kc,
             const float* __restrict__ vc, const int* __restrict__ qlens,
             const int* __restrict__ clens, float* __restrict__ out)
{
    const int qt = blockIdx.x, h = blockIdx.y, b = blockIdx.z;
    const int tid = threadIdx.x, wave = tid >> 6, lane = tid & 63;
    const int g = lane >> 4, lc = lane & 15;
    const int qlen = qlens[b], clen = clens[b];
    const int q0 = qt * QT;
    if (q0 >= qlen) {
        f32x4 z = {0.f, 0.f, 0.f, 0.f};
        #pragma unroll
        for (int i2 = 0; i2 < 8; ++i2) {
            int f = tid + i2 * 256;
            int r = f >> 5, d4 = f & 31;
            *(f32x4*)&out[(((size_t)b * QQ + q0 + r) * HH + h) * DD + d4 * 4] = z;
        }
        return;
    }
    alignas(16) __shared__ unsigned short Kl[KT * DD];
    alignas(16) __shared__ unsigned short Vl[DD * 40];
    alignas(16) __shared__ unsigned short Pl[4][16][40];
    const float psc = 0.08838834764831845f * 1.4426950408889634f;
    const int qrow = q0 + wave * 16 + lc;
    const float* qp = qs + (((size_t)b * QQ + qrow) * HH + h) * DD;
    short8 qf[4];
    #pragma unroll
    for (int c = 0; c < 4; ++c) {
        f32x4 a0 = *(const f32x4*)&qp[c * 32 + g * 8];
        f32x4 a1 = *(const f32x4*)&qp[c * 32 + g * 8 + 4];
        short8 t;
        t[0] = (short)f2bf(a0[0] * psc); t[1] = (short)f2bf(a0[1] * psc);
        t[2] = (short)f2bf(a0[2] * psc); t[3] = (short)f2bf(a0[3] * psc);
        t[4] = (short)f2bf(a1[0] * psc); t[5] = (short)f2bf(a1[1] * psc);
        t[6] = (short)f2bf(a1[2] * psc); t[7] = (short)f2bf(a1[3] * psc);
        qf[c] = t;
    }
    f32x4 o[8];
    #pragma unroll
    for (int n = 0; n < 8; ++n) o[n] = (f32x4){0.f, 0.f, 0.f, 0.f};
    float m_[4] = {-3e38f, -3e38f, -3e38f, -3e38f};
    float l_[4] = {0.f, 0.f, 0.f, 0.f};
    int lim[4];
    #pragma unroll
    for (int qq = 0; qq < 4; ++qq) {
        int i = q0 + wave * 16 + g * 4 + qq;
        lim[qq] = (i < qlen) ? (clen + i + 1) : 0;
    }
    const int kmax = clen + min(q0 + QT, qlen);
    const int nt = (kmax + KT - 1) / KT;
    for (int t = 0; t < nt; ++t) {
        const int pbase = t * KT;
        __syncthreads();
        #pragma unroll
        for (int it = 0; it < 4; ++it) {
            int f = tid + it * 256;
            int key = f >> 5, d4 = f & 31;
            int p = pbase + key;
            const float *srck, *srcv;
            if (p < clen) {
                size_t off = (((size_t)b * SS + p) * HH + h) * DD + d4 * 4;
                srck = kc + off; srcv = vc + off;
            } else {
                int idx = p - clen; if (idx > QQ - 1) idx = QQ - 1;
                size_t off = (((size_t)b * QQ + idx) * HH + h) * DD + d4 * 4;
                srck = ks + off; srcv = vs + off;
            }
            f32x4 kv = *(const f32x4*)srck;
            f32x4 vv = *(const f32x4*)srcv;
            int ei = (key * DD + d4 * 4) ^ ((key & 7) << 3);
            typedef __attribute__((ext_vector_type(4))) unsigned short u16x4;
            u16x4 kb4 = {f2bf(kv[0]), f2bf(kv[1]), f2bf(kv[2]), f2bf(kv[3])};
            *(u16x4*)&Kl[ei] = kb4;
            int d0 = d4 * 4;
            Vl[(d0 + 0) * 40 + key] = f2bf(vv[0]);
            Vl[(d0 + 1) * 40 + key] = f2bf(vv[1]);
            Vl[(d0 + 2) * 40 + key] = f2bf(vv[2]);
            Vl[(d0 + 3) * 40 + key] = f2bf(vv[3]);
        }
        __syncthreads();
        f32x4 sc0 = {0.f, 0.f, 0.f, 0.f}, sc1 = {0.f, 0.f, 0.f, 0.f};
        #pragma unroll
        for (int c = 0; c < 4; ++c) {
            int i0 = (lc * DD + c * 32 + g * 8) ^ ((lc & 7) << 3);
            int i1 = ((16 + lc) * DD + c * 32 + g * 8) ^ (((16 + lc) & 7) << 3);
            short8 k0 = *(const short8*)&Kl[i0];
            short8 k1 = *(const short8*)&Kl[i1];
            sc0 = __builtin_amdgcn_mfma_f32_16x16x32_bf16(qf[c], k0, sc0, 0, 0, 0);
            sc1 = __builtin_amdgcn_mfma_f32_16x16x32_bf16(qf[c], k1, sc1, 0, 0, 0);
        }
        float pr0[4], pr1[4];
        #pragma unroll
        for (int qq = 0; qq < 4; ++qq) {
            float s0 = sc0[qq], s1 = sc1[qq];
            if (pbase + lc >= lim[qq])      s0 = -3e38f;
            if (pbase + 16 + lc >= lim[qq]) s1 = -3e38f;
            float pm = fmaxf(s0, s1);
            #pragma unroll
            for (int d2 = 1; d2 < 16; d2 <<= 1) pm = fmaxf(pm, __shfl_xor(pm, d2));
            float mn = fmaxf(m_[qq], pm);
            float alpha = exp2f(m_[qq] - mn);
            float p0 = exp2f(s0 - mn), p1 = exp2f(s1 - mn);
            float rs = p0 + p1;
            #pragma unroll
            for (int d2 = 1; d2 < 16; d2 <<= 1) rs += __shfl_xor(rs, d2);
            l_[qq] = l_[qq] * alpha + rs;
            m_[qq] = mn;
            pr0[qq] = p0; pr1[qq] = p1;
            #pragma unroll
            for (int n = 0; n < 8; ++n) o[n][qq] *= alpha;
        }
        #pragma unroll
        for (int qq = 0; qq < 4; ++qq) {
            Pl[wave][g * 4 + qq][lc]      = f2bf(pr0[qq]);
            Pl[wave][g * 4 + qq][16 + lc] = f2bf(pr1[qq]);
        }
        short8 pf = *(const short8*)&Pl[wave][lc][g * 8];
        #pragma unroll
        for (int n = 0; n < 8; ++n) {
            short8 vf = *(const short8*)&Vl[(n * 16 + lc) * 40 + g * 8];
            o[n] = __builtin_amdgcn_mfma_f32_16x16x32_bf16(pf, vf, o[n], 0, 0, 0);
        }
    }
    #pragma unroll
    for (int qq = 0; qq < 4; ++qq) {
        int i = q0 + wave * 16 + g * 4 + qq;
        bool val = (i < qlen);
        float inv = val ? (1.0f / l_[qq]) : 0.f;
        size_t ob = (((size_t)b * QQ + i) * HH + h) * DD + lc;
        #pragma unroll
        for (int n = 0; n < 8; ++n)
            out[ob + (size_t)n * 16] = val ? o[n][qq] * inv : 0.f;
    }
}

extern "C" void kernel_launch(void* const* d_in, const int* in_sizes, int n_in,
                              void* d_out, int out_size, void* d_ws, size_t ws_size,
                              hipStream_t stream) {
    const float* qs = (const float*)d_in[0];
    const float* ks = (const float*)d_in[1];
    const float* vs = (const float*)d_in[2];
    const float* kc = (const float*)d_in[3];
    const float* vc = (const float*)d_in[4];
    const int* ql = (const int*)d_in[5];
    const int* cl = (const int*)d_in[6];
    float* o = (float*)d_out;

    const size_t kv_elems = (size_t)BB * HH * NTILES * TILE_ELEMS;
    const size_t kv_bytes = kv_elems * 2 * sizeof(unsigned short);   // 128 MiB
    const size_t need = kv_bytes + 128;

    if (ws_size >= need) {
        unsigned short* Kws = (unsigned short*)d_ws;
        unsigned short* Vws = Kws + kv_elems;
        int* counter = (int*)((char*)d_ws + kv_bytes);
        hipMemsetAsync(counter, 0, sizeof(int), stream);
        dim3 pgrid(NTILES, HH, BB), pblk(256, 1, 1);
        hipLaunchKernelGGL(prep, pgrid, pblk, 0, stream, ks, vs, kc, vc, ql, cl, Kws, Vws);
        dim3 grid(2048, 1, 1), blk(128, 1, 1);
        hipLaunchKernelGGL(segattn_persist, grid, blk, 0, stream, qs, ql, cl, Kws, Vws, o, counter);
    } else {
        dim3 grid(QQ / QT, HH, BB), blk(256, 1, 1);
        hipLaunchKernelGGL(segattn, grid, blk, 0, stream, qs, ks, vs, kc, vc, ql, cl, o);
    }
}

// Round 13
// 215.838 us; speedup vs baseline: 1.6068x; 1.6068x over previous
//
#include <hip/hip_runtime.h>

// R13: R12's single-LDS-buffer pipeline (16.9 KB/block) with the occupancy
// bound fixed: __launch_bounds__(128,3) -> VGPR cap 170 (no spill; R12's
// (128,4) cap 128 spilled everything to scratch, VGPR=64). 6 blocks/CU,
// 3 waves/SIMD (1.5x R11's TLP). Math/prep/queue identical to R11/R12.

#define BB 4
#define QQ 1024
#define SS 2048
#define HH 32
#define DD 128
#define QT 64
#define KT 32
#define NTILES 64
#define TILE_ELEMS 4096
#define NITEMS 2048

typedef __attribute__((ext_vector_type(8))) short short8;
typedef __attribute__((ext_vector_type(4))) float f32x4;
typedef __attribute__((ext_vector_type(16))) float f32x16;
typedef __attribute__((ext_vector_type(4))) unsigned int u32x4;
typedef __attribute__((ext_vector_type(8))) unsigned short u16x8;

__device__ __forceinline__ unsigned short f2bf(float f) {
    unsigned int u = __builtin_bit_cast(unsigned int, f);
    u += 0x7FFFu + ((u >> 16) & 1u);
    return (unsigned short)(u >> 16);
}
__device__ __forceinline__ unsigned int cvtpk(float lo, float hi) {
    unsigned int r;
    asm("v_cvt_pk_bf16_f32 %0, %1, %2" : "=v"(r) : "v"(lo), "v"(hi));
    return r;
}

// ---------------- prep: f32 cache/new -> bf16 32x32-fragment-ordered ws -------
// K tile (4096 hw): idx = c*512 + l*8 + e  ->  K[key=(l&31)][d = c*16 + (l>>5)*8 + e]
// V tile (4096 hw): idx = a*512 + l*8 + e, a=dchunk*2+kc
//                   ->  V[key = kc*16 + (l>>5)*8 + e][d = dchunk*32 + (l&31)]
__global__ __launch_bounds__(256)
void prep(const float* __restrict__ ks, const float* __restrict__ vs,
          const float* __restrict__ kc_, const float* __restrict__ vc,
          const int* __restrict__ qlens, const int* __restrict__ clens,
          unsigned short* __restrict__ Kws, unsigned short* __restrict__ Vws)
{
    const int tile = blockIdx.x, h = blockIdx.y, b = blockIdx.z;
    const int qlen = qlens[b], clen = clens[b];
    if (tile * KT >= clen + qlen) return;
    const int tid = threadIdx.x;
    unsigned short* kout = Kws + (((size_t)b * HH + h) * NTILES + tile) * TILE_ELEMS;
    unsigned short* vout = Vws + (((size_t)b * HH + h) * NTILES + tile) * TILE_ELEMS;

    #pragma unroll
    for (int h2 = 0; h2 < 2; ++h2) {
        const int idx8 = h2 * 2048 + tid * 8;
        const int c = idx8 >> 9, l = (idx8 >> 3) & 63;
        int key = tile * KT + (l & 31);
        const float* src;
        if (key < clen) {
            src = kc_ + (((size_t)b * SS + key) * HH + h) * DD;
        } else {
            int i2 = key - clen; if (i2 > QQ - 1) i2 = QQ - 1;
            src = ks + (((size_t)b * QQ + i2) * HH + h) * DD;
        }
        const int d0 = c * 16 + ((l >> 5) << 3);
        f32x4 a0 = *(const f32x4*)&src[d0];
        f32x4 a1 = *(const f32x4*)&src[d0 + 4];
        u16x8 w;
        w[0] = f2bf(a0[0]); w[1] = f2bf(a0[1]); w[2] = f2bf(a0[2]); w[3] = f2bf(a0[3]);
        w[4] = f2bf(a1[0]); w[5] = f2bf(a1[1]); w[6] = f2bf(a1[2]); w[7] = f2bf(a1[3]);
        *(u16x8*)&kout[idx8] = w;
    }
    #pragma unroll
    for (int h2 = 0; h2 < 2; ++h2) {
        const int idx8 = h2 * 2048 + tid * 8;
        const int a = idx8 >> 9, l = (idx8 >> 3) & 63;
        const int dchunk = a >> 1, kcc = a & 1;
        const int d = dchunk * 32 + (l & 31);
        const int kb = tile * KT + kcc * 16 + ((l >> 5) << 3);
        u16x8 w;
        #pragma unroll
        for (int e = 0; e < 8; ++e) {
            int key = kb + e;
            const float* src;
            if (key < clen) {
                src = vc + (((size_t)b * SS + key) * HH + h) * DD;
            } else {
                int i2 = key - clen; if (i2 > QQ - 1) i2 = QQ - 1;
                src = vs + (((size_t)b * QQ + i2) * HH + h) * DD;
            }
            w[e] = f2bf(src[d]);
        }
        *(u16x8*)&vout[idx8] = w;
    }
}

// ---------------- hot: 128-thr blocks, single LDS buf, 6 blocks/CU ----------
__global__ __launch_bounds__(128, 3)
void segattn_persist(const float* __restrict__ qs, const int* __restrict__ qlens,
                     const int* __restrict__ clens,
                     const unsigned short* __restrict__ Kws,
                     const unsigned short* __restrict__ Vws,
                     float* __restrict__ out, int* __restrict__ counter)
{
    __shared__ int s_item;
    alignas(16) __shared__ unsigned short KVl[8192];  // K [0,4096) V [4096,8192)

    const int tid = threadIdx.x, w = tid >> 6, lane = tid & 63;
    const int q31 = lane & 31, hi = lane >> 5;
    const bool hiL = (hi != 0);
    const float psc = 0.08838834764831845f * 1.4426950408889634f;
    const int sbase = w * 2048 + lane * 8;   // this wave's staging slice base (hw)

    for (;;) {
        if (tid == 0) s_item = atomicAdd(counter, 1);
        __syncthreads();
        const int idx = s_item;
        __syncthreads();
        if (idx >= NITEMS) break;

        const int qt = 15 - (idx >> 7);      // heavy-first pop order (LPT)
        const int b = idx & 3, h = (idx >> 2) & 31;
        const int qlen = qlens[b], clen = clens[b];
        const int q0 = qt * QT;

        if (q0 >= qlen) {                    // fully padded tile -> zeros
            f32x4 z = {0.f, 0.f, 0.f, 0.f};
            #pragma unroll
            for (int i2 = 0; i2 < 16; ++i2) {
                int f = tid + i2 * 128;
                int r = f >> 5, d4 = f & 31;
                *(f32x4*)&out[(((size_t)b * QQ + q0 + r) * HH + h) * DD + d4 * 4] = z;
            }
            continue;
        }

        const int q = q0 + w * 32 + q31;
        const float* qp = qs + (((size_t)b * QQ + q) * HH + h) * DD;
        short8 qf[8];
        #pragma unroll
        for (int c = 0; c < 8; ++c) {
            const int d0 = c * 16 + hi * 8;
            f32x4 a0 = *(const f32x4*)&qp[d0];
            f32x4 a1 = *(const f32x4*)&qp[d0 + 4];
            short8 t;
            t[0] = (short)f2bf(a0[0] * psc); t[1] = (short)f2bf(a0[1] * psc);
            t[2] = (short)f2bf(a0[2] * psc); t[3] = (short)f2bf(a0[3] * psc);
            t[4] = (short)f2bf(a1[0] * psc); t[5] = (short)f2bf(a1[1] * psc);
            t[6] = (short)f2bf(a1[2] * psc); t[7] = (short)f2bf(a1[3] * psc);
            qf[c] = t;
        }

        const int lim_l = (q < qlen) ? (clen + q + 1) : 0;
        const int wq0 = q0 + w * 32;
        const int lim_min = (wq0 + 31 < qlen) ? (clen + wq0 + 1) : 0;

        float m_ = -3e38f, l_ = 0.f;         // lane-partial (pair-reduced at end)
        f32x16 o0 = {0}, o1 = {0}, o2 = {0}, o3 = {0};

        const int kmax = clen + min(q0 + QT, qlen);
        const int nt = (kmax + KT - 1) / KT;
        const unsigned short* Kb = Kws + ((size_t)(b * HH + h)) * NTILES * TILE_ELEMS;
        const unsigned short* Vb = Vws + ((size_t)(b * HH + h)) * NTILES * TILE_ELEMS;

        // ---- prologue: reg-stage tile 0
        u32x4 sk0 = *(const u32x4*)&Kb[sbase];
        u32x4 sk1 = *(const u32x4*)&Kb[sbase + 512];
        u32x4 sk2 = *(const u32x4*)&Kb[sbase + 1024];
        u32x4 sk3 = *(const u32x4*)&Kb[sbase + 1536];
        u32x4 sv0 = *(const u32x4*)&Vb[sbase];
        u32x4 sv1 = *(const u32x4*)&Vb[sbase + 512];
        u32x4 sv2 = *(const u32x4*)&Vb[sbase + 1024];
        u32x4 sv3 = *(const u32x4*)&Vb[sbase + 1536];

        for (int t = 0; t < nt; ++t) {
            // publish tile t (in regs) into the single buffer
            *(u32x4*)&KVl[sbase]               = sk0;
            *(u32x4*)&KVl[sbase + 512]         = sk1;
            *(u32x4*)&KVl[sbase + 1024]        = sk2;
            *(u32x4*)&KVl[sbase + 1536]        = sk3;
            *(u32x4*)&KVl[4096 + sbase]        = sv0;
            *(u32x4*)&KVl[4096 + sbase + 512]  = sv1;
            *(u32x4*)&KVl[4096 + sbase + 1024] = sv2;
            *(u32x4*)&KVl[4096 + sbase + 1536] = sv3;
            // issue loads for tile t+1 (land during compute below)
            const int tnx = (t + 1 < nt) ? t + 1 : (nt - 1);
            const unsigned short* ktn = Kb + (size_t)tnx * TILE_ELEMS;
            const unsigned short* vtn = Vb + (size_t)tnx * TILE_ELEMS;
            sk0 = *(const u32x4*)&ktn[sbase];
            sk1 = *(const u32x4*)&ktn[sbase + 512];
            sk2 = *(const u32x4*)&ktn[sbase + 1024];
            sk3 = *(const u32x4*)&ktn[sbase + 1536];
            sv0 = *(const u32x4*)&vtn[sbase];
            sv1 = *(const u32x4*)&vtn[sbase + 512];
            sv2 = *(const u32x4*)&vtn[sbase + 1024];
            sv3 = *(const u32x4*)&vtn[sbase + 1536];
            asm volatile("s_waitcnt lgkmcnt(0)" ::: "memory");
            __builtin_amdgcn_s_barrier();          // buffer published
            __builtin_amdgcn_sched_barrier(0);

            // ---- compute tile t
            const int pbase = t * KT;
            f32x16 s = {0};
            #pragma unroll
            for (int c = 0; c < 8; ++c) {
                short8 kf = *(const short8*)&KVl[c * 512 + lane * 8];
                s = __builtin_amdgcn_mfma_f32_32x32x16_bf16(kf, qf[c], s, 0, 0, 0);
            }
            if (pbase + KT > lim_min) {
                #pragma unroll
                for (int r = 0; r < 16; ++r) {
                    const int kk = pbase + (r & 3) + ((r >> 2) << 3) + hi * 4;
                    if (kk >= lim_l) s[r] = -3e38f;
                }
            }
            float pm = fmaxf(fmaxf(fmaxf(fmaxf(s[0], s[1]), fmaxf(s[2], s[3])),
                                   fmaxf(fmaxf(s[4], s[5]), fmaxf(s[6], s[7]))),
                             fmaxf(fmaxf(fmaxf(s[8], s[9]), fmaxf(s[10], s[11])),
                                   fmaxf(fmaxf(s[12], s[13]), fmaxf(s[14], s[15]))));
            if (__any(pm > m_ + 8.0f)) {
                pm = fmaxf(pm, __shfl_xor(pm, 32));
                const float mn = fmaxf(m_, pm);
                const float alpha = __builtin_amdgcn_exp2f(m_ - mn);
                m_ = mn;
                l_ *= alpha;
                #pragma unroll
                for (int r = 0; r < 16; ++r) {
                    o0[r] *= alpha; o1[r] *= alpha; o2[r] *= alpha; o3[r] *= alpha;
                }
            }
            float p[16];
            #pragma unroll
            for (int r = 0; r < 16; ++r) p[r] = __builtin_amdgcn_exp2f(s[r] - m_);
            l_ += (((p[0]+p[1])+(p[2]+p[3])) + ((p[4]+p[5])+(p[6]+p[7])))
                + (((p[8]+p[9])+(p[10]+p[11])) + ((p[12]+p[13])+(p[14]+p[15])));

            const unsigned int w0 = cvtpk(p[0],  p[1]);
            const unsigned int w1 = cvtpk(p[2],  p[3]);
            const unsigned int w2 = cvtpk(p[4],  p[5]);
            const unsigned int w3 = cvtpk(p[6],  p[7]);
            const unsigned int w4 = cvtpk(p[8],  p[9]);
            const unsigned int w5 = cvtpk(p[10], p[11]);
            const unsigned int w6 = cvtpk(p[12], p[13]);
            const unsigned int w7 = cvtpk(p[14], p[15]);
            const unsigned int x0 = (unsigned int)__shfl_xor((int)w0, 32);
            const unsigned int x1 = (unsigned int)__shfl_xor((int)w1, 32);
            const unsigned int x2 = (unsigned int)__shfl_xor((int)w2, 32);
            const unsigned int x3 = (unsigned int)__shfl_xor((int)w3, 32);
            const unsigned int x4 = (unsigned int)__shfl_xor((int)w4, 32);
            const unsigned int x5 = (unsigned int)__shfl_xor((int)w5, 32);
            const unsigned int x6 = (unsigned int)__shfl_xor((int)w6, 32);
            const unsigned int x7 = (unsigned int)__shfl_xor((int)w7, 32);
            u32x4 pb0w, pb1w;
            pb0w[0] = hiL ? x2 : w0;  pb0w[1] = hiL ? x3 : w1;
            pb0w[2] = hiL ? w2 : x0;  pb0w[3] = hiL ? w3 : x1;
            pb1w[0] = hiL ? x6 : w4;  pb1w[1] = hiL ? x7 : w5;
            pb1w[2] = hiL ? w6 : x4;  pb1w[3] = hiL ? w7 : x5;
            const short8 pb0 = __builtin_bit_cast(short8, pb0w);
            const short8 pb1 = __builtin_bit_cast(short8, pb1w);

            {
                short8 va = *(const short8*)&KVl[4096 + 0 * 512 + lane * 8];
                short8 vb = *(const short8*)&KVl[4096 + 1 * 512 + lane * 8];
                o0 = __builtin_amdgcn_mfma_f32_32x32x16_bf16(va, pb0, o0, 0, 0, 0);
                o0 = __builtin_amdgcn_mfma_f32_32x32x16_bf16(vb, pb1, o0, 0, 0, 0);
            }
            {
                short8 va = *(const short8*)&KVl[4096 + 2 * 512 + lane * 8];
                short8 vb = *(const short8*)&KVl[4096 + 3 * 512 + lane * 8];
                o1 = __builtin_amdgcn_mfma_f32_32x32x16_bf16(va, pb0, o1, 0, 0, 0);
                o1 = __builtin_amdgcn_mfma_f32_32x32x16_bf16(vb, pb1, o1, 0, 0, 0);
            }
            {
                short8 va = *(const short8*)&KVl[4096 + 4 * 512 + lane * 8];
                short8 vb = *(const short8*)&KVl[4096 + 5 * 512 + lane * 8];
                o2 = __builtin_amdgcn_mfma_f32_32x32x16_bf16(va, pb0, o2, 0, 0, 0);
                o2 = __builtin_amdgcn_mfma_f32_32x32x16_bf16(vb, pb1, o2, 0, 0, 0);
            }
            {
                short8 va = *(const short8*)&KVl[4096 + 6 * 512 + lane * 8];
                short8 vb = *(const short8*)&KVl[4096 + 7 * 512 + lane * 8];
                o3 = __builtin_amdgcn_mfma_f32_32x32x16_bf16(va, pb0, o3, 0, 0, 0);
                o3 = __builtin_amdgcn_mfma_f32_32x32x16_bf16(vb, pb1, o3, 0, 0, 0);
            }

            asm volatile("s_waitcnt lgkmcnt(0)" ::: "memory");
            __builtin_amdgcn_s_barrier();          // all waves done reading buf
            __builtin_amdgcn_sched_barrier(0);
        }

        // ---- epilogue: pair-reduce l, store O
        float lt = l_ + __shfl_xor(l_, 32);
        const bool val = (q < qlen);
        const float inv = val ? (1.0f / lt) : 0.f;
        float* op = out + (((size_t)b * QQ + q) * HH + h) * DD;
        #pragma unroll
        for (int rr = 0; rr < 4; ++rr) {
            f32x4 wv;
            const int d0 = rr * 8 + hi * 4;
            wv[0] = o0[rr*4+0]*inv; wv[1] = o0[rr*4+1]*inv;
            wv[2] = o0[rr*4+2]*inv; wv[3] = o0[rr*4+3]*inv;
            *(f32x4*)&op[d0] = wv;
            wv[0] = o1[rr*4+0]*inv; wv[1] = o1[rr*4+1]*inv;
            wv[2] = o1[rr*4+2]*inv; wv[3] = o1[rr*4+3]*inv;
            *(f32x4*)&op[32 + d0] = wv;
            wv[0] = o2[rr*4+0]*inv; wv[1] = o2[rr*4+1]*inv;
            wv[2] = o2[rr*4+2]*inv; wv[3] = o2[rr*4+3]*inv;
            *(f32x4*)&op[64 + d0] = wv;
            wv[0] = o3[rr*4+0]*inv; wv[1] = o3[rr*4+1]*inv;
            wv[2] = o3[rr*4+2]*inv; wv[3] = o3[rr*4+3]*inv;
            *(f32x4*)&op[96 + d0] = wv;
        }
    }
}

// ---------------- R1 fallback (proven) if ws too small ----------------
__global__ __launch_bounds__(256)
void segattn(const float* __restrict__ qs, const float* __restrict__ ks,
             const float* __restrict__ vs, const float* __restrict__ kc,
             const float* __restrict__ vc, const int* __restrict__ qlens,
             const int* __restrict__ clens, float* __restrict__ out)
{
    const int qt = blockIdx.x, h = blockIdx.y, b = blockIdx.z;
    const int tid = threadIdx.x, wave = tid >> 6, lane = tid & 63;
    const int g = lane >> 4, lc = lane & 15;
    const int qlen = qlens[b], clen = clens[b];
    const int q0 = qt * QT;
    if (q0 >= qlen) {
        f32x4 z = {0.f, 0.f, 0.f, 0.f};
        #pragma unroll
        for (int i2 = 0; i2 < 8; ++i2) {
            int f = tid + i2 * 256;
            int r = f >> 5, d4 = f & 31;
            *(f32x4*)&out[(((size_t)b * QQ + q0 + r) * HH + h) * DD + d4 * 4] = z;
        }
        return;
    }
    alignas(16) __shared__ unsigned short Kl[KT * DD];
    alignas(16) __shared__ unsigned short Vl[DD * 40];
    alignas(16) __shared__ unsigned short Pl[4][16][40];
    const float psc = 0.08838834764831845f * 1.4426950408889634f;
    const int qrow = q0 + wave * 16 + lc;
    const float* qp = qs + (((size_t)b * QQ + qrow) * HH + h) * DD;
    short8 qf[4];
    #pragma unroll
    for (int c = 0; c < 4; ++c) {
        f32x4 a0 = *(const f32x4*)&qp[c * 32 + g * 8];
        f32x4 a1 = *(const f32x4*)&qp[c * 32 + g * 8 + 4];
        short8 t;
        t[0] = (short)f2bf(a0[0] * psc); t[1] = (short)f2bf(a0[1] * psc);
        t[2] = (short)f2bf(a0[2] * psc); t[3] = (short)f2bf(a0[3] * psc);
        t[4] = (short)f2bf(a1[0] * psc); t[5] = (short)f2bf(a1[1] * psc);
        t[6] = (short)f2bf(a1[2] * psc); t[7] = (short)f2bf(a1[3] * psc);
        qf[c] = t;
    }
    f32x4 o[8];
    #pragma unroll
    for (int n = 0; n < 8; ++n) o[n] = (f32x4){0.f, 0.f, 0.f, 0.f};
    float m_[4] = {-3e38f, -3e38f, -3e38f, -3e38f};
    float l_[4] = {0.f, 0.f, 0.f, 0.f};
    int lim[4];
    #pragma unroll
    for (int qq = 0; qq < 4; ++qq) {
        int i = q0 + wave * 16 + g * 4 + qq;
        lim[qq] = (i < qlen) ? (clen + i + 1) : 0;
    }
    const int kmax = clen + min(q0 + QT, qlen);
    const int nt = (kmax + KT - 1) / KT;
    for (int t = 0; t < nt; ++t) {
        const int pbase = t * KT;
        __syncthreads();
        #pragma unroll
        for (int it = 0; it < 4; ++it) {
            int f = tid + it * 256;
            int key = f >> 5, d4 = f & 31;
            int p = pbase + key;
            const float *srck, *srcv;
            if (p < clen) {
                size_t off = (((size_t)b * SS + p) * HH + h) * DD + d4 * 4;
                srck = kc + off; srcv = vc + off;
            } else {
                int idx = p - clen; if (idx > QQ - 1) idx = QQ - 1;
                size_t off = (((size_t)b * QQ + idx) * HH + h) * DD + d4 * 4;
                srck = ks + off; srcv = vs + off;
            }
            f32x4 kv = *(const f32x4*)srck;
            f32x4 vv = *(const f32x4*)srcv;
            int ei = (key * DD + d4 * 4) ^ ((key & 7) << 3);
            typedef __attribute__((ext_vector_type(4))) unsigned short u16x4;
            u16x4 kb4 = {f2bf(kv[0]), f2bf(kv[1]), f2bf(kv[2]), f2bf(kv[3])};
            *(u16x4*)&Kl[ei] = kb4;
            int d0 = d4 * 4;
            Vl[(d0 + 0) * 40 + key] = f2bf(vv[0]);
            Vl[(d0 + 1) * 40 + key] = f2bf(vv[1]);
            Vl[(d0 + 2) * 40 + key] = f2bf(vv[2]);
            Vl[(d0 + 3) * 40 + key] = f2bf(vv[3]);
        }
        __syncthreads();
        f32x4 sc0 = {0.f, 0.f, 0.f, 0.f}, sc1 = {0.f, 0.f, 0.f, 0.f};
        #pragma unroll
        for (int c = 0; c < 4; ++c) {
            int i0 = (lc * DD + c * 32 + g * 8) ^ ((lc & 7) << 3);
            int i1 = ((16 + lc) * DD + c * 32 + g * 8) ^ (((16 + lc) & 7) << 3);
            short8 k0 = *(const short8*)&Kl[i0];
            short8 k1 = *(const short8*)&Kl[i1];
            sc0 = __builtin_amdgcn_mfma_f32_16x16x32_bf16(qf[c], k0, sc0, 0, 0, 0);
            sc1 = __builtin_amdgcn_mfma_f32_16x16x32_bf16(qf[c], k1, sc1, 0, 0, 0);
        }
        float pr0[4], pr1[4];
        #pragma unroll
        for (int qq = 0; qq < 4; ++qq) {
            float s0 = sc0[qq], s1 = sc1[qq];
            if (pbase + lc >= lim[qq])      s0 = -3e38f;
            if (pbase + 16 + lc >= lim[qq]) s1 = -3e38f;
            float pm = fmaxf(s0, s1);
            #pragma unroll
            for (int d2 = 1; d2 < 16; d2 <<= 1) pm = fmaxf(pm, __shfl_xor(pm, d2));
            float mn = fmaxf(m_[qq], pm);
            float alpha = exp2f(m_[qq] - mn);
            float p0 = exp2f(s0 - mn), p1 = exp2f(s1 - mn);
            float rs = p0 + p1;
            #pragma unroll
            for (int d2 = 1; d2 < 16; d2 <<= 1) rs += __shfl_xor(rs, d2);
            l_[qq] = l_[qq] * alpha + rs;
            m_[qq] = mn;
            pr0[qq] = p0; pr1[qq] = p1;
            #pragma unroll
            for (int n = 0; n < 8; ++n) o[n][qq] *= alpha;
        }
        #pragma unroll
        for (int qq = 0; qq < 4; ++qq) {
            Pl[wave][g * 4 + qq][lc]      = f2bf(pr0[qq]);
            Pl[wave][g * 4 + qq][16 + lc] = f2bf(pr1[qq]);
        }
        short8 pf = *(const short8*)&Pl[wave][lc][g * 8];
        #pragma unroll
        for (int n = 0; n < 8; ++n) {
            short8 vf = *(const short8*)&Vl[(n * 16 + lc) * 40 + g * 8];
            o[n] = __builtin_amdgcn_mfma_f32_16x16x32_bf16(pf, vf, o[n], 0, 0, 0);
        }
    }
    #pragma unroll
    for (int qq = 0; qq < 4; ++qq) {
        int i = q0 + wave * 16 + g * 4 + qq;
        bool val = (i < qlen);
        float inv = val ? (1.0f / l_[qq]) : 0.f;
        size_t ob = (((size_t)b * QQ + i) * HH + h) * DD + lc;
        #pragma unroll
        for (int n = 0; n < 8; ++n)
            out[ob + (size_t)n * 16] = val ? o[n][qq] * inv : 0.f;
    }
}

extern "C" void kernel_launch(void* const* d_in, const int* in_sizes, int n_in,
                              void* d_out, int out_size, void* d_ws, size_t ws_size,
                              hipStream_t stream) {
    const float* qs = (const float*)d_in[0];
    const float* ks = (const float*)d_in[1];
    const float* vs = (const float*)d_in[2];
    const float* kc = (const float*)d_in[3];
    const float* vc = (const float*)d_in[4];
    const int* ql = (const int*)d_in[5];
    const int* cl = (const int*)d_in[6];
    float* o = (float*)d_out;

    const size_t kv_elems = (size_t)BB * HH * NTILES * TILE_ELEMS;
    const size_t kv_bytes = kv_elems * 2 * sizeof(unsigned short);   // 128 MiB
    const size_t need = kv_bytes + 128;

    if (ws_size >= need) {
        unsigned short* Kws = (unsigned short*)d_ws;
        unsigned short* Vws = Kws + kv_elems;
        int* counter = (int*)((char*)d_ws + kv_bytes);
        hipMemsetAsync(counter, 0, sizeof(int), stream);
        dim3 pgrid(NTILES, HH, BB), pblk(256, 1, 1);
        hipLaunchKernelGGL(prep, pgrid, pblk, 0, stream, ks, vs, kc, vc, ql, cl, Kws, Vws);
        dim3 grid(2048, 1, 1), blk(128, 1, 1);
        hipLaunchKernelGGL(segattn_persist, grid, blk, 0, stream, qs, ql, cl, Kws, Vws, o, counter);
    } else {
        dim3 grid(QQ / QT, HH, BB), blk(256, 1, 1);
        hipLaunchKernelGGL(segattn, grid, blk, 0, stream, qs, ks, vs, kc, vc, ql, cl, o);
    }
}

// Round 14
// 184.491 us; speedup vs baseline: 1.8798x; 1.1699x over previous
//
#include <hip/hip_runtime.h>

// R14: R11 geometry (2-wave/128-thr blocks, 32x32 MFMA, 33KB LDS, (128,2),
// persistent heavy-first queue) with a PAIR-PHASE loop: the two 16.5KB LDS
// buffers hold a 64-key pair; per phase {compute both subtiles with FUSED
// softmax -> barrier -> publish next pair from regs -> issue loads pair+2 ->
// barrier}. 1 barrier/32-key tile (was 2), half the softmax checks, 2x
// prefetch distance. Odd-nt tail: subtile B force-masked (huge pbase).

#define BB 4
#define QQ 1024
#define SS 2048
#define HH 32
#define DD 128
#define QT 64
#define KT 32
#define NTILES 64
#define TILE_ELEMS 4096
#define NITEMS 2048

typedef __attribute__((ext_vector_type(8))) short short8;
typedef __attribute__((ext_vector_type(4))) float f32x4;
typedef __attribute__((ext_vector_type(16))) float f32x16;
typedef __attribute__((ext_vector_type(4))) unsigned int u32x4;
typedef __attribute__((ext_vector_type(8))) unsigned short u16x8;

__device__ __forceinline__ unsigned short f2bf(float f) {
    unsigned int u = __builtin_bit_cast(unsigned int, f);
    u += 0x7FFFu + ((u >> 16) & 1u);
    return (unsigned short)(u >> 16);
}
__device__ __forceinline__ unsigned int cvtpk(float lo, float hi) {
    unsigned int r;
    asm("v_cvt_pk_bf16_f32 %0, %1, %2" : "=v"(r) : "v"(lo), "v"(hi));
    return r;
}

// ---------------- prep: f32 cache/new -> bf16 32x32-fragment-ordered ws -------
// K tile (4096 hw): idx = c*512 + l*8 + e  ->  K[key=(l&31)][d = c*16 + (l>>5)*8 + e]
// V tile (4096 hw): idx = a*512 + l*8 + e, a=dchunk*2+kc
//                   ->  V[key = kc*16 + (l>>5)*8 + e][d = dchunk*32 + (l&31)]
__global__ __launch_bounds__(256)
void prep(const float* __restrict__ ks, const float* __restrict__ vs,
          const float* __restrict__ kc_, const float* __restrict__ vc,
          const int* __restrict__ qlens, const int* __restrict__ clens,
          unsigned short* __restrict__ Kws, unsigned short* __restrict__ Vws)
{
    const int tile = blockIdx.x, h = blockIdx.y, b = blockIdx.z;
    const int qlen = qlens[b], clen = clens[b];
    if (tile * KT >= clen + qlen) return;
    const int tid = threadIdx.x;
    unsigned short* kout = Kws + (((size_t)b * HH + h) * NTILES + tile) * TILE_ELEMS;
    unsigned short* vout = Vws + (((size_t)b * HH + h) * NTILES + tile) * TILE_ELEMS;

    #pragma unroll
    for (int h2 = 0; h2 < 2; ++h2) {
        const int idx8 = h2 * 2048 + tid * 8;
        const int c = idx8 >> 9, l = (idx8 >> 3) & 63;
        int key = tile * KT + (l & 31);
        const float* src;
        if (key < clen) {
            src = kc_ + (((size_t)b * SS + key) * HH + h) * DD;
        } else {
            int i2 = key - clen; if (i2 > QQ - 1) i2 = QQ - 1;
            src = ks + (((size_t)b * QQ + i2) * HH + h) * DD;
        }
        const int d0 = c * 16 + ((l >> 5) << 3);
        f32x4 a0 = *(const f32x4*)&src[d0];
        f32x4 a1 = *(const f32x4*)&src[d0 + 4];
        u16x8 w;
        w[0] = f2bf(a0[0]); w[1] = f2bf(a0[1]); w[2] = f2bf(a0[2]); w[3] = f2bf(a0[3]);
        w[4] = f2bf(a1[0]); w[5] = f2bf(a1[1]); w[6] = f2bf(a1[2]); w[7] = f2bf(a1[3]);
        *(u16x8*)&kout[idx8] = w;
    }
    #pragma unroll
    for (int h2 = 0; h2 < 2; ++h2) {
        const int idx8 = h2 * 2048 + tid * 8;
        const int a = idx8 >> 9, l = (idx8 >> 3) & 63;
        const int dchunk = a >> 1, kcc = a & 1;
        const int d = dchunk * 32 + (l & 31);
        const int kb = tile * KT + kcc * 16 + ((l >> 5) << 3);
        u16x8 w;
        #pragma unroll
        for (int e = 0; e < 8; ++e) {
            int key = kb + e;
            const float* src;
            if (key < clen) {
                src = vc + (((size_t)b * SS + key) * HH + h) * DD;
            } else {
                int i2 = key - clen; if (i2 > QQ - 1) i2 = QQ - 1;
                src = vs + (((size_t)b * QQ + i2) * HH + h) * DD;
            }
            w[e] = f2bf(src[d]);
        }
        *(u16x8*)&vout[idx8] = w;
    }
}

// ---------------- hot: pair-phase loop, 2 waves x 32 rows ----------------
__global__ __launch_bounds__(128, 2)
void segattn_persist(const float* __restrict__ qs, const int* __restrict__ qlens,
                     const int* __restrict__ clens,
                     const unsigned short* __restrict__ Kws,
                     const unsigned short* __restrict__ Vws,
                     float* __restrict__ out, int* __restrict__ counter)
{
    __shared__ int s_item;
    alignas(16) __shared__ unsigned short KVl[2][8192];  // per buf: K [0,4096) V [4096,8192)

    const int tid = threadIdx.x, w = tid >> 6, lane = tid & 63;
    const int q31 = lane & 31, hi = lane >> 5;
    const bool hiL = (hi != 0);
    const float psc = 0.08838834764831845f * 1.4426950408889634f;
    const int sbase = w * 2048 + lane * 8;   // this wave's staging slice base (hw)

    for (;;) {
        if (tid == 0) s_item = atomicAdd(counter, 1);
        __syncthreads();
        const int idx = s_item;
        __syncthreads();
        if (idx >= NITEMS) break;

        const int qt = 15 - (idx >> 7);      // heavy-first pop order (LPT)
        const int b = idx & 3, h = (idx >> 2) & 31;
        const int qlen = qlens[b], clen = clens[b];
        const int q0 = qt * QT;

        if (q0 >= qlen) {                    // fully padded tile -> zeros
            f32x4 z = {0.f, 0.f, 0.f, 0.f};
            #pragma unroll
            for (int i2 = 0; i2 < 16; ++i2) {
                int f = tid + i2 * 128;
                int r = f >> 5, d4 = f & 31;
                *(f32x4*)&out[(((size_t)b * QQ + q0 + r) * HH + h) * DD + d4 * 4] = z;
            }
            continue;
        }

        const int q = q0 + w * 32 + q31;
        const float* qp = qs + (((size_t)b * QQ + q) * HH + h) * DD;
        short8 qf[8];
        #pragma unroll
        for (int c = 0; c < 8; ++c) {
            const int d0 = c * 16 + hi * 8;
            f32x4 a0 = *(const f32x4*)&qp[d0];
            f32x4 a1 = *(const f32x4*)&qp[d0 + 4];
            short8 t;
            t[0] = (short)f2bf(a0[0] * psc); t[1] = (short)f2bf(a0[1] * psc);
            t[2] = (short)f2bf(a0[2] * psc); t[3] = (short)f2bf(a0[3] * psc);
            t[4] = (short)f2bf(a1[0] * psc); t[5] = (short)f2bf(a1[1] * psc);
            t[6] = (short)f2bf(a1[2] * psc); t[7] = (short)f2bf(a1[3] * psc);
            qf[c] = t;
        }

        const int lim_l = (q < qlen) ? (clen + q + 1) : 0;
        const int wq0 = q0 + w * 32;
        const int lim_min = (wq0 + 31 < qlen) ? (clen + wq0 + 1) : 0;

        float m_ = -3e38f, l_ = 0.f;         // lane-partial (pair-reduced at end)
        f32x16 o0 = {0}, o1 = {0}, o2 = {0}, o3 = {0};

        const int kmax = clen + min(q0 + QT, qlen);
        const int nt = (kmax + KT - 1) / KT;
        const unsigned short* Kb = Kws + ((size_t)(b * HH + h)) * NTILES * TILE_ELEMS;
        const unsigned short* Vb = Vws + ((size_t)(b * HH + h)) * NTILES * TILE_ELEMS;

        // ---- prologue: stage tiles 0,1 into bufs 0,1 directly
        {
            const int t1x = (nt > 1) ? 1 : 0;
            const unsigned short* k1p = Kb + (size_t)t1x * TILE_ELEMS;
            const unsigned short* v1p = Vb + (size_t)t1x * TILE_ELEMS;
            #pragma unroll
            for (int j = 0; j < 4; ++j) {
                u32x4 a0 = *(const u32x4*)&Kb[sbase + j * 512];
                u32x4 a1 = *(const u32x4*)&Vb[sbase + j * 512];
                u32x4 b0 = *(const u32x4*)&k1p[sbase + j * 512];
                u32x4 b1 = *(const u32x4*)&v1p[sbase + j * 512];
                *(u32x4*)&KVl[0][sbase + j * 512]        = a0;
                *(u32x4*)&KVl[0][4096 + sbase + j * 512] = a1;
                *(u32x4*)&KVl[1][sbase + j * 512]        = b0;
                *(u32x4*)&KVl[1][4096 + sbase + j * 512] = b1;
            }
            asm volatile("s_waitcnt lgkmcnt(0)" ::: "memory");
            __builtin_amdgcn_s_barrier();
            __builtin_amdgcn_sched_barrier(0);
        }
        // reg-stage pair 1 (tiles 2,3; clamped)
        const int t2x = (nt > 2) ? 2 : (nt - 1);
        const int t3x = (nt > 3) ? 3 : (nt - 1);
        const unsigned short* k2p = Kb + (size_t)t2x * TILE_ELEMS;
        const unsigned short* v2p = Vb + (size_t)t2x * TILE_ELEMS;
        const unsigned short* k3p = Kb + (size_t)t3x * TILE_ELEMS;
        const unsigned short* v3p = Vb + (size_t)t3x * TILE_ELEMS;
        u32x4 ska0 = *(const u32x4*)&k2p[sbase];
        u32x4 ska1 = *(const u32x4*)&k2p[sbase + 512];
        u32x4 ska2 = *(const u32x4*)&k2p[sbase + 1024];
        u32x4 ska3 = *(const u32x4*)&k2p[sbase + 1536];
        u32x4 sva0 = *(const u32x4*)&v2p[sbase];
        u32x4 sva1 = *(const u32x4*)&v2p[sbase + 512];
        u32x4 sva2 = *(const u32x4*)&v2p[sbase + 1024];
        u32x4 sva3 = *(const u32x4*)&v2p[sbase + 1536];
        u32x4 skb0 = *(const u32x4*)&k3p[sbase];
        u32x4 skb1 = *(const u32x4*)&k3p[sbase + 512];
        u32x4 skb2 = *(const u32x4*)&k3p[sbase + 1024];
        u32x4 skb3 = *(const u32x4*)&k3p[sbase + 1536];
        u32x4 svb0 = *(const u32x4*)&v3p[sbase];
        u32x4 svb1 = *(const u32x4*)&v3p[sbase + 512];
        u32x4 svb2 = *(const u32x4*)&v3p[sbase + 1024];
        u32x4 svb3 = *(const u32x4*)&v3p[sbase + 1536];

        for (int tp = 0; tp < nt; tp += 2) {
            // ---- compute subtile A (buf0) and B (buf1), fused softmax
            const int pbA = tp * KT;
            const bool bReal = (tp + 1 < nt);
            const int pbB = bReal ? (tp + 1) * KT : (1 << 29);  // huge -> fully masked

            f32x16 sA = {0}, sB = {0};
            #pragma unroll
            for (int c = 0; c < 8; ++c) {
                short8 kfA = *(const short8*)&KVl[0][c * 512 + lane * 8];
                short8 kfB = *(const short8*)&KVl[1][c * 512 + lane * 8];
                sA = __builtin_amdgcn_mfma_f32_32x32x16_bf16(kfA, qf[c], sA, 0, 0, 0);
                sB = __builtin_amdgcn_mfma_f32_32x32x16_bf16(kfB, qf[c], sB, 0, 0, 0);
            }
            if (pbA + KT > lim_min) {
                #pragma unroll
                for (int r = 0; r < 16; ++r) {
                    const int kk = pbA + (r & 3) + ((r >> 2) << 3) + hi * 4;
                    if (kk >= lim_l) sA[r] = -3e38f;
                }
            }
            if (pbB + KT > lim_min) {
                #pragma unroll
                for (int r = 0; r < 16; ++r) {
                    const int kk = pbB + (r & 3) + ((r >> 2) << 3) + hi * 4;
                    if (kk >= lim_l) sB[r] = -3e38f;
                }
            }
            float pm = -3e38f;
            #pragma unroll
            for (int r = 0; r < 16; ++r) pm = fmaxf(pm, fmaxf(sA[r], sB[r]));
            if (__any(pm > m_ + 8.0f)) {
                pm = fmaxf(pm, __shfl_xor(pm, 32));
                const float mn = fmaxf(m_, pm);
                const float alpha = __builtin_amdgcn_exp2f(m_ - mn);
                m_ = mn;
                l_ *= alpha;
                #pragma unroll
                for (int r = 0; r < 16; ++r) {
                    o0[r] *= alpha; o1[r] *= alpha; o2[r] *= alpha; o3[r] *= alpha;
                }
            }
            float pA[16], pB[16];
            #pragma unroll
            for (int r = 0; r < 16; ++r) {
                pA[r] = __builtin_amdgcn_exp2f(sA[r] - m_);
                pB[r] = __builtin_amdgcn_exp2f(sB[r] - m_);
            }
            float ls = 0.f;
            #pragma unroll
            for (int r = 0; r < 16; ++r) ls += pA[r] + pB[r];
            l_ += ls;

            // pack P for both subtiles
            unsigned int wA[8], wB[8];
            #pragma unroll
            for (int j = 0; j < 8; ++j) {
                wA[j] = cvtpk(pA[2 * j], pA[2 * j + 1]);
                wB[j] = cvtpk(pB[2 * j], pB[2 * j + 1]);
            }
            unsigned int xA[8], xB[8];
            #pragma unroll
            for (int j = 0; j < 8; ++j) {
                xA[j] = (unsigned int)__shfl_xor((int)wA[j], 32);
                xB[j] = (unsigned int)__shfl_xor((int)wB[j], 32);
            }
            u32x4 pa0w, pa1w, pb0w, pb1w;
            pa0w[0] = hiL ? xA[2] : wA[0];  pa0w[1] = hiL ? xA[3] : wA[1];
            pa0w[2] = hiL ? wA[2] : xA[0];  pa0w[3] = hiL ? wA[3] : xA[1];
            pa1w[0] = hiL ? xA[6] : wA[4];  pa1w[1] = hiL ? xA[7] : wA[5];
            pa1w[2] = hiL ? wA[6] : xA[4];  pa1w[3] = hiL ? wA[7] : xA[5];
            pb0w[0] = hiL ? xB[2] : wB[0];  pb0w[1] = hiL ? xB[3] : wB[1];
            pb0w[2] = hiL ? wB[2] : xB[0];  pb0w[3] = hiL ? wB[3] : xB[1];
            pb1w[0] = hiL ? xB[6] : wB[4];  pb1w[1] = hiL ? xB[7] : wB[5];
            pb1w[2] = hiL ? wB[6] : xB[4];  pb1w[3] = hiL ? wB[7] : xB[5];
            const short8 paf0 = __builtin_bit_cast(short8, pa0w);
            const short8 paf1 = __builtin_bit_cast(short8, pa1w);
            const short8 pbf0 = __builtin_bit_cast(short8, pb0w);
            const short8 pbf1 = __builtin_bit_cast(short8, pb1w);

            // PV for both subtiles
            #pragma unroll
            for (int dc = 0; dc < 4; ++dc) {
                short8 vaA = *(const short8*)&KVl[0][4096 + (2 * dc) * 512 + lane * 8];
                short8 vbA = *(const short8*)&KVl[0][4096 + (2 * dc + 1) * 512 + lane * 8];
                short8 vaB = *(const short8*)&KVl[1][4096 + (2 * dc) * 512 + lane * 8];
                short8 vbB = *(const short8*)&KVl[1][4096 + (2 * dc + 1) * 512 + lane * 8];
                f32x16* od = (dc == 0) ? &o0 : (dc == 1) ? &o1 : (dc == 2) ? &o2 : &o3;
                *od = __builtin_amdgcn_mfma_f32_32x32x16_bf16(vaA, paf0, *od, 0, 0, 0);
                *od = __builtin_amdgcn_mfma_f32_32x32x16_bf16(vbA, paf1, *od, 0, 0, 0);
                *od = __builtin_amdgcn_mfma_f32_32x32x16_bf16(vaB, pbf0, *od, 0, 0, 0);
                *od = __builtin_amdgcn_mfma_f32_32x32x16_bf16(vbB, pbf1, *od, 0, 0, 0);
            }

            asm volatile("s_waitcnt lgkmcnt(0)" ::: "memory");
            __builtin_amdgcn_s_barrier();          // done reading bufs
            __builtin_amdgcn_sched_barrier(0);

            // ---- publish pair tp+2,tp+3 (in regs) into bufs
            *(u32x4*)&KVl[0][sbase]               = ska0;
            *(u32x4*)&KVl[0][sbase + 512]         = ska1;
            *(u32x4*)&KVl[0][sbase + 1024]        = ska2;
            *(u32x4*)&KVl[0][sbase + 1536]        = ska3;
            *(u32x4*)&KVl[0][4096 + sbase]        = sva0;
            *(u32x4*)&KVl[0][4096 + sbase + 512]  = sva1;
            *(u32x4*)&KVl[0][4096 + sbase + 1024] = sva2;
            *(u32x4*)&KVl[0][4096 + sbase + 1536] = sva3;
            *(u32x4*)&KVl[1][sbase]               = skb0;
            *(u32x4*)&KVl[1][sbase + 512]         = skb1;
            *(u32x4*)&KVl[1][sbase + 1024]        = skb2;
            *(u32x4*)&KVl[1][sbase + 1536]        = skb3;
            *(u32x4*)&KVl[1][4096 + sbase]        = svb0;
            *(u32x4*)&KVl[1][4096 + sbase + 512]  = svb1;
            *(u32x4*)&KVl[1][4096 + sbase + 1024] = svb2;
            *(u32x4*)&KVl[1][4096 + sbase + 1536] = svb3;

            // ---- issue loads for pair tp+4,tp+5 (clamped)
            const int t4x = (tp + 4 < nt) ? tp + 4 : (nt - 1);
            const int t5x = (tp + 5 < nt) ? tp + 5 : (nt - 1);
            const unsigned short* k4p = Kb + (size_t)t4x * TILE_ELEMS;
            const unsigned short* v4p = Vb + (size_t)t4x * TILE_ELEMS;
            const unsigned short* k5p = Kb + (size_t)t5x * TILE_ELEMS;
            const unsigned short* v5p = Vb + (size_t)t5x * TILE_ELEMS;
            ska0 = *(const u32x4*)&k4p[sbase];
            ska1 = *(const u32x4*)&k4p[sbase + 512];
            ska2 = *(const u32x4*)&k4p[sbase + 1024];
            ska3 = *(const u32x4*)&k4p[sbase + 1536];
            sva0 = *(const u32x4*)&v4p[sbase];
            sva1 = *(const u32x4*)&v4p[sbase + 512];
            sva2 = *(const u32x4*)&v4p[sbase + 1024];
            sva3 = *(const u32x4*)&v4p[sbase + 1536];
            skb0 = *(const u32x4*)&k5p[sbase];
            skb1 = *(const u32x4*)&k5p[sbase + 512];
            skb2 = *(const u32x4*)&k5p[sbase + 1024];
            skb3 = *(const u32x4*)&k5p[sbase + 1536];
            svb0 = *(const u32x4*)&v5p[sbase];
            svb1 = *(const u32x4*)&v5p[sbase + 512];
            svb2 = *(const u32x4*)&v5p[sbase + 1024];
            svb3 = *(const u32x4*)&v5p[sbase + 1536];

            asm volatile("s_waitcnt lgkmcnt(0)" ::: "memory");
            __builtin_amdgcn_s_barrier();          // bufs published
            __builtin_amdgcn_sched_barrier(0);
        }

        // ---- epilogue: pair-reduce l, store O
        float lt = l_ + __shfl_xor(l_, 32);
        const bool val = (q < qlen);
        const float inv = val ? (1.0f / lt) : 0.f;
        float* op = out + (((size_t)b * QQ + q) * HH + h) * DD;
        #pragma unroll
        for (int rr = 0; rr < 4; ++rr) {
            f32x4 wv;
            const int d0 = rr * 8 + hi * 4;
            wv[0] = o0[rr*4+0]*inv; wv[1] = o0[rr*4+1]*inv;
            wv[2] = o0[rr*4+2]*inv; wv[3] = o0[rr*4+3]*inv;
            *(f32x4*)&op[d0] = wv;
            wv[0] = o1[rr*4+0]*inv; wv[1] = o1[rr*4+1]*inv;
            wv[2] = o1[rr*4+2]*inv; wv[3] = o1[rr*4+3]*inv;
            *(f32x4*)&op[32 + d0] = wv;
            wv[0] = o2[rr*4+0]*inv; wv[1] = o2[rr*4+1]*inv;
            wv[2] = o2[rr*4+2]*inv; wv[3] = o2[rr*4+3]*inv;
            *(f32x4*)&op[64 + d0] = wv;
            wv[0] = o3[rr*4+0]*inv; wv[1] = o3[rr*4+1]*inv;
            wv[2] = o3[rr*4+2]*inv; wv[3] = o3[rr*4+3]*inv;
            *(f32x4*)&op[96 + d0] = wv;
        }
    }
}

// ---------------- R1 fallback (proven) if ws too small ----------------
__global__ __launch_bounds__(256)
void segattn(const float* __restrict__ qs, const float* __restrict__ ks,
             const float* __restrict__ vs, const float* __restrict__ kc,
             const float* __restrict__ vc, const int* __restrict__ qlens,
             const int* __restrict__ clens, float* __restrict__ out)
{
    const int qt = blockIdx.x, h = blockIdx.y, b = blockIdx.z;
    const int tid = threadIdx.x, wave = tid >> 6, lane = tid & 63;
    const int g = lane >> 4, lc = lane & 15;
    const int qlen = qlens[b], clen = clens[b];
    const int q0 = qt * QT;
    if (q0 >= qlen) {
        f32x4 z = {0.f, 0.f, 0.f, 0.f};
        #pragma unroll
        for (int i2 = 0; i2 < 8; ++i2) {
            int f = tid + i2 * 256;
            int r = f >> 5, d4 = f & 31;
            *(f32x4*)&out[(((size_t)b * QQ + q0 + r) * HH + h) * DD + d4 * 4] = z;
        }
        return;
    }
    alignas(16) __shared__ unsigned short Kl[KT * DD];
    alignas(16) __shared__ unsigned short Vl[DD * 40];
    alignas(16) __shared__ unsigned short Pl[4][16][40];
    const float psc = 0.08838834764831845f * 1.4426950408889634f;
    const int qrow = q0 + wave * 16 + lc;
    const float* qp = qs + (((size_t)b * QQ + qrow) * HH + h) * DD;
    short8 qf[4];
    #pragma unroll
    for (int c = 0; c < 4; ++c) {
        f32x4 a0 = *(const f32x4*)&qp[c * 32 + g * 8];
        f32x4 a1 = *(const f32x4*)&qp[c * 32 + g * 8 + 4];
        short8 t;
        t[0] = (short)f2bf(a0[0] * psc); t[1] = (short)f2bf(a0[1] * psc);
        t[2] = (short)f2bf(a0[2] * psc); t[3] = (short)f2bf(a0[3] * psc);
        t[4] = (short)f2bf(a1[0] * psc); t[5] = (short)f2bf(a1[1] * psc);
        t[6] = (short)f2bf(a1[2] * psc); t[7] = (short)f2bf(a1[3] * psc);
        qf[c] = t;
    }
    f32x4 o[8];
    #pragma unroll
    for (int n = 0; n < 8; ++n) o[n] = (f32x4){0.f, 0.f, 0.f, 0.f};
    float m_[4] = {-3e38f, -3e38f, -3e38f, -3e38f};
    float l_[4] = {0.f, 0.f, 0.f, 0.f};
    int lim[4];
    #pragma unroll
    for (int qq = 0; qq < 4; ++qq) {
        int i = q0 + wave * 16 + g * 4 + qq;
        lim[qq] = (i < qlen) ? (clen + i + 1) : 0;
    }
    const int kmax = clen + min(q0 + QT, qlen);
    const int nt = (kmax + KT - 1) / KT;
    for (int t = 0; t < nt; ++t) {
        const int pbase = t * KT;
        __syncthreads();
        #pragma unroll
        for (int it = 0; it < 4; ++it) {
            int f = tid + it * 256;
            int key = f >> 5, d4 = f & 31;
            int p = pbase + key;
            const float *srck, *srcv;
            if (p < clen) {
                size_t off = (((size_t)b * SS + p) * HH + h) * DD + d4 * 4;
                srck = kc + off; srcv = vc + off;
            } else {
                int idx = p - clen; if (idx > QQ - 1) idx = QQ - 1;
                size_t off = (((size_t)b * QQ + idx) * HH + h) * DD + d4 * 4;
                srck = ks + off; srcv = vs + off;
            }
            f32x4 kv = *(const f32x4*)srck;
            f32x4 vv = *(const f32x4*)srcv;
            int ei = (key * DD + d4 * 4) ^ ((key & 7) << 3);
            typedef __attribute__((ext_vector_type(4))) unsigned short u16x4;
            u16x4 kb4 = {f2bf(kv[0]), f2bf(kv[1]), f2bf(kv[2]), f2bf(kv[3])};
            *(u16x4*)&Kl[ei] = kb4;
            int d0 = d4 * 4;
            Vl[(d0 + 0) * 40 + key] = f2bf(vv[0]);
            Vl[(d0 + 1) * 40 + key] = f2bf(vv[1]);
            Vl[(d0 + 2) * 40 + key] = f2bf(vv[2]);
            Vl[(d0 + 3) * 40 + key] = f2bf(vv[3]);
        }
        __syncthreads();
        f32x4 sc0 = {0.f, 0.f, 0.f, 0.f}, sc1 = {0.f, 0.f, 0.f, 0.f};
        #pragma unroll
        for (int c = 0; c < 4; ++c) {
            int i0 = (lc * DD + c * 32 + g * 8) ^ ((lc & 7) << 3);
            int i1 = ((16 + lc) * DD + c * 32 + g * 8) ^ (((16 + lc) & 7) << 3);
            short8 k0 = *(const short8*)&Kl[i0];
            short8 k1 = *(const short8*)&Kl[i1];
            sc0 = __builtin_amdgcn_mfma_f32_16x16x32_bf16(qf[c], k0, sc0, 0, 0, 0);
            sc1 = __builtin_amdgcn_mfma_f32_16x16x32_bf16(qf[c], k1, sc1, 0, 0, 0);
        }
        float pr0[4], pr1[4];
        #pragma unroll
        for (int qq = 0; qq < 4; ++qq) {
            float s0 = sc0[qq], s1 = sc1[qq];
            if (pbase + lc >= lim[qq])      s0 = -3e38f;
            if (pbase + 16 + lc >= lim[qq]) s1 = -3e38f;
            float pm = fmaxf(s0, s1);
            #pragma unroll
            for (int d2 = 1; d2 < 16; d2 <<= 1) pm = fmaxf(pm, __shfl_xor(pm, d2));
            float mn = fmaxf(m_[qq], pm);
            float alpha = exp2f(m_[qq] - mn);
            float p0 = exp2f(s0 - mn), p1 = exp2f(s1 - mn);
            float rs = p0 + p1;
            #pragma unroll
            for (int d2 = 1; d2 < 16; d2 <<= 1) rs += __shfl_xor(rs, d2);
            l_[qq] = l_[qq] * alpha + rs;
            m_[qq] = mn;
            pr0[qq] = p0; pr1[qq] = p1;
            #pragma unroll
            for (int n = 0; n < 8; ++n) o[n][qq] *= alpha;
        }
        #pragma unroll
        for (int qq = 0; qq < 4; ++qq) {
            Pl[wave][g * 4 + qq][lc]      = f2bf(pr0[qq]);
            Pl[wave][g * 4 + qq][16 + lc] = f2bf(pr1[qq]);
        }
        short8 pf = *(const short8*)&Pl[wave][lc][g * 8];
        #pragma unroll
        for (int n = 0; n < 8; ++n) {
            short8 vf = *(const short8*)&Vl[(n * 16 + lc) * 40 + g * 8];
            o[n] = __builtin_amdgcn_mfma_f32_16x16x32_bf16(pf, vf, o[n], 0, 0, 0);
        }
    }
    #pragma unroll
    for (int qq = 0; qq < 4; ++qq) {
        int i = q0 + wave * 16 + g * 4 + qq;
        bool val = (i < qlen);
        float inv = val ? (1.0f / l_[qq]) : 0.f;
        size_t ob = (((size_t)b * QQ + i) * HH + h) * DD + lc;
        #pragma unroll
        for (int n = 0; n < 8; ++n)
            out[ob + (size_t)n * 16] = val ? o[n][qq] * inv : 0.f;
    }
}

extern "C" void kernel_launch(void* const* d_in, const int* in_sizes, int n_in,
                              void* d_out, int out_size, void* d_ws, size_t ws_size,
                              hipStream_t stream) {
    const float* qs = (const float*)d_in[0];
    const float* ks = (const float*)d_in[1];
    const float* vs = (const float*)d_in[2];
    const float* kc = (const float*)d_in[3];
    const float* vc = (const float*)d_in[4];
    const int* ql = (const int*)d_in[5];
    const int* cl = (const int*)d_in[6];
    float* o = (float*)d_out;

    const size_t kv_elems = (size_t)BB * HH * NTILES * TILE_ELEMS;
    const size_t kv_bytes = kv_elems * 2 * sizeof(unsigned short);   // 128 MiB
    const size_t need = kv_bytes + 128;

    if (ws_size >= need) {
        unsigned short* Kws = (unsigned short*)d_ws;
        unsigned short* Vws = Kws + kv_elems;
        int* counter = (int*)((char*)d_ws + kv_bytes);
        hipMemsetAsync(counter, 0, sizeof(int), stream);
        dim3 pgrid(NTILES, HH, BB), pblk(256, 1, 1);
        hipLaunchKernelGGL(prep, pgrid, pblk, 0, stream, ks, vs, kc, vc, ql, cl, Kws, Vws);
        dim3 grid(2048, 1, 1), blk(128, 1, 1);
        hipLaunchKernelGGL(segattn_persist, grid, blk, 0, stream, qs, ql, cl, Kws, Vws, o, counter);
    } else {
        dim3 grid(QQ / QT, HH, BB), blk(256, 1, 1);
        hipLaunchKernelGGL(segattn, grid, blk, 0, stream, qs, ks, vs, kc, vc, ql, cl, o);
    }
}

// Round 15
// 173.201 us; speedup vs baseline: 2.0024x; 1.0652x over previous
//
#include <hip/hip_runtime.h>

// R15: R11 geometry (2-wave/128-thr blocks, 32x32 MFMA, 33KB LDS dbuf,
// (128,2), persistent heavy-first queue, defer-max, mask-skip) with staging
// via __builtin_amdgcn_global_load_lds (zero staging VGPRs / VALU):
// per tile {issue 8 glds for t+1 -> buf[nb]; compute tile t from buf[cur];
// vmcnt(0); s_barrier}. ONE barrier per tile. setprio(1) around MFMAs (T5).

#define BB 4
#define QQ 1024
#define SS 2048
#define HH 32
#define DD 128
#define QT 64
#define KT 32
#define NTILES 64
#define TILE_ELEMS 4096
#define NITEMS 2048

typedef __attribute__((ext_vector_type(8))) short short8;
typedef __attribute__((ext_vector_type(4))) float f32x4;
typedef __attribute__((ext_vector_type(16))) float f32x16;
typedef __attribute__((ext_vector_type(4))) unsigned int u32x4;
typedef __attribute__((ext_vector_type(8))) unsigned short u16x8;

__device__ __forceinline__ unsigned short f2bf(float f) {
    unsigned int u = __builtin_bit_cast(unsigned int, f);
    u += 0x7FFFu + ((u >> 16) & 1u);
    return (unsigned short)(u >> 16);
}
__device__ __forceinline__ unsigned int cvtpk(float lo, float hi) {
    unsigned int r;
    asm("v_cvt_pk_bf16_f32 %0, %1, %2" : "=v"(r) : "v"(lo), "v"(hi));
    return r;
}
__device__ __forceinline__ void glds16(const unsigned short* g, unsigned short* l) {
    __builtin_amdgcn_global_load_lds(
        (const __attribute__((address_space(1))) unsigned int*)g,
        (__attribute__((address_space(3))) unsigned int*)l, 16, 0, 0);
}

// ---------------- prep: f32 cache/new -> bf16 32x32-fragment-ordered ws -------
// K tile (4096 hw): idx = c*512 + l*8 + e  ->  K[key=(l&31)][d = c*16 + (l>>5)*8 + e]
// V tile (4096 hw): idx = a*512 + l*8 + e, a=dchunk*2+kc
//                   ->  V[key = kc*16 + (l>>5)*8 + e][d = dchunk*32 + (l&31)]
__global__ __launch_bounds__(256)
void prep(const float* __restrict__ ks, const float* __restrict__ vs,
          const float* __restrict__ kc_, const float* __restrict__ vc,
          const int* __restrict__ qlens, const int* __restrict__ clens,
          unsigned short* __restrict__ Kws, unsigned short* __restrict__ Vws)
{
    const int tile = blockIdx.x, h = blockIdx.y, b = blockIdx.z;
    const int qlen = qlens[b], clen = clens[b];
    if (tile * KT >= clen + qlen) return;
    const int tid = threadIdx.x;
    unsigned short* kout = Kws + (((size_t)b * HH + h) * NTILES + tile) * TILE_ELEMS;
    unsigned short* vout = Vws + (((size_t)b * HH + h) * NTILES + tile) * TILE_ELEMS;

    #pragma unroll
    for (int h2 = 0; h2 < 2; ++h2) {
        const int idx8 = h2 * 2048 + tid * 8;
        const int c = idx8 >> 9, l = (idx8 >> 3) & 63;
        int key = tile * KT + (l & 31);
        const float* src;
        if (key < clen) {
            src = kc_ + (((size_t)b * SS + key) * HH + h) * DD;
        } else {
            int i2 = key - clen; if (i2 > QQ - 1) i2 = QQ - 1;
            src = ks + (((size_t)b * QQ + i2) * HH + h) * DD;
        }
        const int d0 = c * 16 + ((l >> 5) << 3);
        f32x4 a0 = *(const f32x4*)&src[d0];
        f32x4 a1 = *(const f32x4*)&src[d0 + 4];
        u16x8 w;
        w[0] = f2bf(a0[0]); w[1] = f2bf(a0[1]); w[2] = f2bf(a0[2]); w[3] = f2bf(a0[3]);
        w[4] = f2bf(a1[0]); w[5] = f2bf(a1[1]); w[6] = f2bf(a1[2]); w[7] = f2bf(a1[3]);
        *(u16x8*)&kout[idx8] = w;
    }
    #pragma unroll
    for (int h2 = 0; h2 < 2; ++h2) {
        const int idx8 = h2 * 2048 + tid * 8;
        const int a = idx8 >> 9, l = (idx8 >> 3) & 63;
        const int dchunk = a >> 1, kcc = a & 1;
        const int d = dchunk * 32 + (l & 31);
        const int kb = tile * KT + kcc * 16 + ((l >> 5) << 3);
        u16x8 w;
        #pragma unroll
        for (int e = 0; e < 8; ++e) {
            int key = kb + e;
            const float* src;
            if (key < clen) {
                src = vc + (((size_t)b * SS + key) * HH + h) * DD;
            } else {
                int i2 = key - clen; if (i2 > QQ - 1) i2 = QQ - 1;
                src = vs + (((size_t)b * QQ + i2) * HH + h) * DD;
            }
            w[e] = f2bf(src[d]);
        }
        *(u16x8*)&vout[idx8] = w;
    }
}

// ---------------- hot: glds double-buffer, 1 barrier/tile ----------------
__global__ __launch_bounds__(128, 2)
void segattn_persist(const float* __restrict__ qs, const int* __restrict__ qlens,
                     const int* __restrict__ clens,
                     const unsigned short* __restrict__ Kws,
                     const unsigned short* __restrict__ Vws,
                     float* __restrict__ out, int* __restrict__ counter)
{
    __shared__ int s_item;
    alignas(16) __shared__ unsigned short KVl[2][8192];  // per buf: K [0,4096) V [4096,8192)

    const int tid = threadIdx.x, w = tid >> 6, lane = tid & 63;
    const int q31 = lane & 31, hi = lane >> 5;
    const bool hiL = (hi != 0);
    const float psc = 0.08838834764831845f * 1.4426950408889634f;
    const int sbase = w * 2048 + lane * 8;   // per-lane global slice offset (hw)
    const int lbase = w * 2048;              // wave-uniform LDS slice base (hw)

    for (;;) {
        if (tid == 0) s_item = atomicAdd(counter, 1);
        __syncthreads();
        const int idx = s_item;
        __syncthreads();
        if (idx >= NITEMS) break;

        const int qt = 15 - (idx >> 7);      // heavy-first pop order (LPT)
        const int b = idx & 3, h = (idx >> 2) & 31;
        const int qlen = qlens[b], clen = clens[b];
        const int q0 = qt * QT;

        if (q0 >= qlen) {                    // fully padded tile -> zeros
            f32x4 z = {0.f, 0.f, 0.f, 0.f};
            #pragma unroll
            for (int i2 = 0; i2 < 16; ++i2) {
                int f = tid + i2 * 128;
                int r = f >> 5, d4 = f & 31;
                *(f32x4*)&out[(((size_t)b * QQ + q0 + r) * HH + h) * DD + d4 * 4] = z;
            }
            continue;
        }

        const int q = q0 + w * 32 + q31;
        const float* qp = qs + (((size_t)b * QQ + q) * HH + h) * DD;
        short8 qf[8];
        #pragma unroll
        for (int c = 0; c < 8; ++c) {
            const int d0 = c * 16 + hi * 8;
            f32x4 a0 = *(const f32x4*)&qp[d0];
            f32x4 a1 = *(const f32x4*)&qp[d0 + 4];
            short8 t;
            t[0] = (short)f2bf(a0[0] * psc); t[1] = (short)f2bf(a0[1] * psc);
            t[2] = (short)f2bf(a0[2] * psc); t[3] = (short)f2bf(a0[3] * psc);
            t[4] = (short)f2bf(a1[0] * psc); t[5] = (short)f2bf(a1[1] * psc);
            t[6] = (short)f2bf(a1[2] * psc); t[7] = (short)f2bf(a1[3] * psc);
            qf[c] = t;
        }

        const int lim_l = (q < qlen) ? (clen + q + 1) : 0;
        const int wq0 = q0 + w * 32;
        const int lim_min = (wq0 + 31 < qlen) ? (clen + wq0 + 1) : 0;

        float m_ = -3e38f, l_ = 0.f;         // lane-partial (pair-reduced at end)
        f32x16 o0 = {0}, o1 = {0}, o2 = {0}, o3 = {0};

        const int kmax = clen + min(q0 + QT, qlen);
        const int nt = (kmax + KT - 1) / KT;
        const unsigned short* Kb = Kws + ((size_t)(b * HH + h)) * NTILES * TILE_ELEMS;
        const unsigned short* Vb = Vws + ((size_t)(b * HH + h)) * NTILES * TILE_ELEMS;

        // ---- prologue: glds tile 0 -> buf0
        #pragma unroll
        for (int j = 0; j < 4; ++j) {
            glds16(&Kb[sbase + j * 512], &KVl[0][lbase + j * 512]);
            glds16(&Vb[sbase + j * 512], &KVl[0][4096 + lbase + j * 512]);
        }
        asm volatile("s_waitcnt vmcnt(0)" ::: "memory");
        __builtin_amdgcn_s_barrier();
        __builtin_amdgcn_sched_barrier(0);

        int cur = 0;
        for (int t = 0; t < nt; ++t) {
            const int nb = cur ^ 1;
            // issue glds for tile t+1 into buf[nb] (lands during compute)
            const int tnx = (t + 1 < nt) ? t + 1 : (nt - 1);
            const unsigned short* ktn = Kb + (size_t)tnx * TILE_ELEMS;
            const unsigned short* vtn = Vb + (size_t)tnx * TILE_ELEMS;
            #pragma unroll
            for (int j = 0; j < 4; ++j) {
                glds16(&ktn[sbase + j * 512], &KVl[nb][lbase + j * 512]);
                glds16(&vtn[sbase + j * 512], &KVl[nb][4096 + lbase + j * 512]);
            }

            // ---- compute tile t from buf[cur]
            const unsigned short* Kc = &KVl[cur][0];
            const int pbase = t * KT;
            f32x16 s = {0};
            __builtin_amdgcn_s_setprio(1);
            #pragma unroll
            for (int c = 0; c < 8; ++c) {
                short8 kf = *(const short8*)&Kc[c * 512 + lane * 8];
                s = __builtin_amdgcn_mfma_f32_32x32x16_bf16(kf, qf[c], s, 0, 0, 0);
            }
            __builtin_amdgcn_s_setprio(0);
            if (pbase + KT > lim_min) {
                #pragma unroll
                for (int r = 0; r < 16; ++r) {
                    const int kk = pbase + (r & 3) + ((r >> 2) << 3) + hi * 4;
                    if (kk >= lim_l) s[r] = -3e38f;
                }
            }
            float pm = fmaxf(fmaxf(fmaxf(fmaxf(s[0], s[1]), fmaxf(s[2], s[3])),
                                   fmaxf(fmaxf(s[4], s[5]), fmaxf(s[6], s[7]))),
                             fmaxf(fmaxf(fmaxf(s[8], s[9]), fmaxf(s[10], s[11])),
                                   fmaxf(fmaxf(s[12], s[13]), fmaxf(s[14], s[15]))));
            if (__any(pm > m_ + 8.0f)) {
                pm = fmaxf(pm, __shfl_xor(pm, 32));
                const float mn = fmaxf(m_, pm);
                const float alpha = __builtin_amdgcn_exp2f(m_ - mn);
                m_ = mn;
                l_ *= alpha;
                #pragma unroll
                for (int r = 0; r < 16; ++r) {
                    o0[r] *= alpha; o1[r] *= alpha; o2[r] *= alpha; o3[r] *= alpha;
                }
            }
            float p[16];
            #pragma unroll
            for (int r = 0; r < 16; ++r) p[r] = __builtin_amdgcn_exp2f(s[r] - m_);
            l_ += (((p[0]+p[1])+(p[2]+p[3])) + ((p[4]+p[5])+(p[6]+p[7])))
                + (((p[8]+p[9])+(p[10]+p[11])) + ((p[12]+p[13])+(p[14]+p[15])));

            const unsigned int w0 = cvtpk(p[0],  p[1]);
            const unsigned int w1 = cvtpk(p[2],  p[3]);
            const unsigned int w2 = cvtpk(p[4],  p[5]);
            const unsigned int w3 = cvtpk(p[6],  p[7]);
            const unsigned int w4 = cvtpk(p[8],  p[9]);
            const unsigned int w5 = cvtpk(p[10], p[11]);
            const unsigned int w6 = cvtpk(p[12], p[13]);
            const unsigned int w7 = cvtpk(p[14], p[15]);
            const unsigned int x0 = (unsigned int)__shfl_xor((int)w0, 32);
            const unsigned int x1 = (unsigned int)__shfl_xor((int)w1, 32);
            const unsigned int x2 = (unsigned int)__shfl_xor((int)w2, 32);
            const unsigned int x3 = (unsigned int)__shfl_xor((int)w3, 32);
            const unsigned int x4 = (unsigned int)__shfl_xor((int)w4, 32);
            const unsigned int x5 = (unsigned int)__shfl_xor((int)w5, 32);
            const unsigned int x6 = (unsigned int)__shfl_xor((int)w6, 32);
            const unsigned int x7 = (unsigned int)__shfl_xor((int)w7, 32);
            u32x4 pb0w, pb1w;
            pb0w[0] = hiL ? x2 : w0;  pb0w[1] = hiL ? x3 : w1;
            pb0w[2] = hiL ? w2 : x0;  pb0w[3] = hiL ? w3 : x1;
            pb1w[0] = hiL ? x6 : w4;  pb1w[1] = hiL ? x7 : w5;
            pb1w[2] = hiL ? w6 : x4;  pb1w[3] = hiL ? w7 : x5;
            const short8 pb0 = __builtin_bit_cast(short8, pb0w);
            const short8 pb1 = __builtin_bit_cast(short8, pb1w);

            __builtin_amdgcn_s_setprio(1);
            {
                short8 va = *(const short8*)&Kc[4096 + 0 * 512 + lane * 8];
                short8 vb = *(const short8*)&Kc[4096 + 1 * 512 + lane * 8];
                o0 = __builtin_amdgcn_mfma_f32_32x32x16_bf16(va, pb0, o0, 0, 0, 0);
                o0 = __builtin_amdgcn_mfma_f32_32x32x16_bf16(vb, pb1, o0, 0, 0, 0);
            }
            {
                short8 va = *(const short8*)&Kc[4096 + 2 * 512 + lane * 8];
                short8 vb = *(const short8*)&Kc[4096 + 3 * 512 + lane * 8];
                o1 = __builtin_amdgcn_mfma_f32_32x32x16_bf16(va, pb0, o1, 0, 0, 0);
                o1 = __builtin_amdgcn_mfma_f32_32x32x16_bf16(vb, pb1, o1, 0, 0, 0);
            }
            {
                short8 va = *(const short8*)&Kc[4096 + 4 * 512 + lane * 8];
                short8 vb = *(const short8*)&Kc[4096 + 5 * 512 + lane * 8];
                o2 = __builtin_amdgcn_mfma_f32_32x32x16_bf16(va, pb0, o2, 0, 0, 0);
                o2 = __builtin_amdgcn_mfma_f32_32x32x16_bf16(vb, pb1, o2, 0, 0, 0);
            }
            {
                short8 va = *(const short8*)&Kc[4096 + 6 * 512 + lane * 8];
                short8 vb = *(const short8*)&Kc[4096 + 7 * 512 + lane * 8];
                o3 = __builtin_amdgcn_mfma_f32_32x32x16_bf16(va, pb0, o3, 0, 0, 0);
                o3 = __builtin_amdgcn_mfma_f32_32x32x16_bf16(vb, pb1, o3, 0, 0, 0);
            }
            __builtin_amdgcn_s_setprio(0);

            asm volatile("s_waitcnt vmcnt(0)" ::: "memory");  // t+1 glds landed
            __builtin_amdgcn_s_barrier();                     // all waves done w/ cur
            __builtin_amdgcn_sched_barrier(0);
            cur = nb;
        }

        // ---- epilogue: pair-reduce l, store O
        float lt = l_ + __shfl_xor(l_, 32);
        const bool val = (q < qlen);
        const float inv = val ? (1.0f / lt) : 0.f;
        float* op = out + (((size_t)b * QQ + q) * HH + h) * DD;
        #pragma unroll
        for (int rr = 0; rr < 4; ++rr) {
            f32x4 wv;
            const int d0 = rr * 8 + hi * 4;
            wv[0] = o0[rr*4+0]*inv; wv[1] = o0[rr*4+1]*inv;
            wv[2] = o0[rr*4+2]*inv; wv[3] = o0[rr*4+3]*inv;
            *(f32x4*)&op[d0] = wv;
            wv[0] = o1[rr*4+0]*inv; wv[1] = o1[rr*4+1]*inv;
            wv[2] = o1[rr*4+2]*inv; wv[3] = o1[rr*4+3]*inv;
            *(f32x4*)&op[32 + d0] = wv;
            wv[0] = o2[rr*4+0]*inv; wv[1] = o2[rr*4+1]*inv;
            wv[2] = o2[rr*4+2]*inv; wv[3] = o2[rr*4+3]*inv;
            *(f32x4*)&op[64 + d0] = wv;
            wv[0] = o3[rr*4+0]*inv; wv[1] = o3[rr*4+1]*inv;
            wv[2] = o3[rr*4+2]*inv; wv[3] = o3[rr*4+3]*inv;
            *(f32x4*)&op[96 + d0] = wv;
        }
    }
}

// ---------------- R1 fallback (proven) if ws too small ----------------
__global__ __launch_bounds__(256)
void segattn(const float* __restrict__ qs, const float* __restrict__ ks,
             const float* __restrict__ vs, const float* __restrict__ kc,
             const float* __restrict__ vc, const int* __restrict__ qlens,
             const int* __restrict__ clens, float* __restrict__ out)
{
    const int qt = blockIdx.x, h = blockIdx.y, b = blockIdx.z;
    const int tid = threadIdx.x, wave = tid >> 6, lane = tid & 63;
    const int g = lane >> 4, lc = lane & 15;
    const int qlen = qlens[b], clen = clens[b];
    const int q0 = qt * QT;
    if (q0 >= qlen) {
        f32x4 z = {0.f, 0.f, 0.f, 0.f};
        #pragma unroll
        for (int i2 = 0; i2 < 8; ++i2) {
            int f = tid + i2 * 256;
            int r = f >> 5, d4 = f & 31;
            *(f32x4*)&out[(((size_t)b * QQ + q0 + r) * HH + h) * DD + d4 * 4] = z;
        }
        return;
    }
    alignas(16) __shared__ unsigned short Kl[KT * DD];
    alignas(16) __shared__ unsigned short Vl[DD * 40];
    alignas(16) __shared__ unsigned short Pl[4][16][40];
    const float psc = 0.08838834764831845f * 1.4426950408889634f;
    const int qrow = q0 + wave * 16 + lc;
    const float* qp = qs + (((size_t)b * QQ + qrow) * HH + h) * DD;
    short8 qf[4];
    #pragma unroll
    for (int c = 0; c < 4; ++c) {
        f32x4 a0 = *(const f32x4*)&qp[c * 32 + g * 8];
        f32x4 a1 = *(const f32x4*)&qp[c * 32 + g * 8 + 4];
        short8 t;
        t[0] = (short)f2bf(a0[0] * psc); t[1] = (short)f2bf(a0[1] * psc);
        t[2] = (short)f2bf(a0[2] * psc); t[3] = (short)f2bf(a0[3] * psc);
        t[4] = (short)f2bf(a1[0] * psc); t[5] = (short)f2bf(a1[1] * psc);
        t[6] = (short)f2bf(a1[2] * psc); t[7] = (short)f2bf(a1[3] * psc);
        qf[c] = t;
    }
    f32x4 o[8];
    #pragma unroll
    for (int n = 0; n < 8; ++n) o[n] = (f32x4){0.f, 0.f, 0.f, 0.f};
    float m_[4] = {-3e38f, -3e38f, -3e38f, -3e38f};
    float l_[4] = {0.f, 0.f, 0.f, 0.f};
    int lim[4];
    #pragma unroll
    for (int qq = 0; qq < 4; ++qq) {
        int i = q0 + wave * 16 + g * 4 + qq;
        lim[qq] = (i < qlen) ? (clen + i + 1) : 0;
    }
    const int kmax = clen + min(q0 + QT, qlen);
    const int nt = (kmax + KT - 1) / KT;
    for (int t = 0; t < nt; ++t) {
        const int pbase = t * KT;
        __syncthreads();
        #pragma unroll
        for (int it = 0; it < 4; ++it) {
            int f = tid + it * 256;
            int key = f >> 5, d4 = f & 31;
            int p = pbase + key;
            const float *srck, *srcv;
            if (p < clen) {
                size_t off = (((size_t)b * SS + p) * HH + h) * DD + d4 * 4;
                srck = kc + off; srcv = vc + off;
            } else {
                int idx = p - clen; if (idx > QQ - 1) idx = QQ - 1;
                size_t off = (((size_t)b * QQ + idx) * HH + h) * DD + d4 * 4;
                srck = ks + off; srcv = vs + off;
            }
            f32x4 kv = *(const f32x4*)srck;
            f32x4 vv = *(const f32x4*)srcv;
            int ei = (key * DD + d4 * 4) ^ ((key & 7) << 3);
            typedef __attribute__((ext_vector_type(4))) unsigned short u16x4;
            u16x4 kb4 = {f2bf(kv[0]), f2bf(kv[1]), f2bf(kv[2]), f2bf(kv[3])};
            *(u16x4*)&Kl[ei] = kb4;
            int d0 = d4 * 4;
            Vl[(d0 + 0) * 40 + key] = f2bf(vv[0]);
            Vl[(d0 + 1) * 40 + key] = f2bf(vv[1]);
            Vl[(d0 + 2) * 40 + key] = f2bf(vv[2]);
            Vl[(d0 + 3) * 40 + key] = f2bf(vv[3]);
        }
        __syncthreads();
        f32x4 sc0 = {0.f, 0.f, 0.f, 0.f}, sc1 = {0.f, 0.f, 0.f, 0.f};
        #pragma unroll
        for (int c = 0; c < 4; ++c) {
            int i0 = (lc * DD + c * 32 + g * 8) ^ ((lc & 7) << 3);
            int i1 = ((16 + lc) * DD + c * 32 + g * 8) ^ (((16 + lc) & 7) << 3);
            short8 k0 = *(const short8*)&Kl[i0];
            short8 k1 = *(const short8*)&Kl[i1];
            sc0 = __builtin_amdgcn_mfma_f32_16x16x32_bf16(qf[c], k0, sc0, 0, 0, 0);
            sc1 = __builtin_amdgcn_mfma_f32_16x16x32_bf16(qf[c], k1, sc1, 0, 0, 0);
        }
        float pr0[4], pr1[4];
        #pragma unroll
        for (int qq = 0; qq < 4; ++qq) {
            float s0 = sc0[qq], s1 = sc1[qq];
            if (pbase + lc >= lim[qq])      s0 = -3e38f;
            if (pbase + 16 + lc >= lim[qq]) s1 = -3e38f;
            float pm = fmaxf(s0, s1);
            #pragma unroll
            for (int d2 = 1; d2 < 16; d2 <<= 1) pm = fmaxf(pm, __shfl_xor(pm, d2));
            float mn = fmaxf(m_[qq], pm);
            float alpha = exp2f(m_[qq] - mn);
            float p0 = exp2f(s0 - mn), p1 = exp2f(s1 - mn);
            float rs = p0 + p1;
            #pragma unroll
            for (int d2 = 1; d2 < 16; d2 <<= 1) rs += __shfl_xor(rs, d2);
            l_[qq] = l_[qq] * alpha + rs;
            m_[qq] = mn;
            pr0[qq] = p0; pr1[qq] = p1;
            #pragma unroll
            for (int n = 0; n < 8; ++n) o[n][qq] *= alpha;
        }
        #pragma unroll
        for (int qq = 0; qq < 4; ++qq) {
            Pl[wave][g * 4 + qq][lc]      = f2bf(pr0[qq]);
            Pl[wave][g * 4 + qq][16 + lc] = f2bf(pr1[qq]);
        }
        short8 pf = *(const short8*)&Pl[wave][lc][g * 8];
        #pragma unroll
        for (int n = 0; n < 8; ++n) {
            short8 vf = *(const short8*)&Vl[(n * 16 + lc) * 40 + g * 8];
            o[n] = __builtin_amdgcn_mfma_f32_16x16x32_bf16(pf, vf, o[n], 0, 0, 0);
        }
    }
    #pragma unroll
    for (int qq = 0; qq < 4; ++qq) {
        int i = q0 + wave * 16 + g * 4 + qq;
        bool val = (i < qlen);
        float inv = val ? (1.0f / l_[qq]) : 0.f;
        size_t ob = (((size_t)b * QQ + i) * HH + h) * DD + lc;
        #pragma unroll
        for (int n = 0; n < 8; ++n)
            out[ob + (size_t)n * 16] = val ? o[n][qq] * inv : 0.f;
    }
}

extern "C" void kernel_launch(void* const* d_in, const int* in_sizes, int n_in,
                              void* d_out, int out_size, void* d_ws, size_t ws_size,
                              hipStream_t stream) {
    const float* qs = (const float*)d_in[0];
    const float* ks = (const float*)d_in[1];
    const float* vs = (const float*)d_in[2];
    const float* kc = (const float*)d_in[3];
    const float* vc = (const float*)d_in[4];
    const int* ql = (const int*)d_in[5];
    const int* cl = (const int*)d_in[6];
    float* o = (float*)d_out;

    const size_t kv_elems = (size_t)BB * HH * NTILES * TILE_ELEMS;
    const size_t kv_bytes = kv_elems * 2 * sizeof(unsigned short);   // 128 MiB
    const size_t need = kv_bytes + 128;

    if (ws_size >= need) {
        unsigned short* Kws = (unsigned short*)d_ws;
        unsigned short* Vws = Kws + kv_elems;
        int* counter = (int*)((char*)d_ws + kv_bytes);
        hipMemsetAsync(counter, 0, sizeof(int), stream);
        dim3 pgrid(NTILES, HH, BB), pblk(256, 1, 1);
        hipLaunchKernelGGL(prep, pgrid, pblk, 0, stream, ks, vs, kc, vc, ql, cl, Kws, Vws);
        dim3 grid(1024, 1, 1), blk(128, 1, 1);
        hipLaunchKernelGGL(segattn_persist, grid, blk, 0, stream, qs, ql, cl, Kws, Vws, o, counter);
    } else {
        dim3 grid(QQ / QT, HH, BB), blk(256, 1, 1);
        hipLaunchKernelGGL(segattn, grid, blk, 0, stream, qs, ks, vs, kc, vc, ql, cl, o);
    }
}